// Round 1
// baseline (7840.521 us; speedup 1.0000x reference)
//
#include <hip/hip_runtime.h>

#define N_NODES 100000
#define N_EDGES 300000
#define N_GRAPHS 2048
#define IN_DIM 38
#define HID 256
#define LAYERS 5
#define BN_EPS 1e-5f

// ---------------- projection: h = x @ Wp + bp  ([N,38]@[38,256]) -------------
#define NPB 4
__global__ __launch_bounds__(256) void proj_kernel(
    const float* __restrict__ x, const float* __restrict__ Wp,
    const float* __restrict__ bp, float* __restrict__ h) {
    __shared__ float xs[NPB][IN_DIM];
    int c = threadIdx.x;
    int n0 = blockIdx.x * NPB;
    for (int i = threadIdx.x; i < NPB * IN_DIM; i += 256) {
        int j = i / IN_DIM, k = i % IN_DIM;
        int n = n0 + j;
        xs[j][k] = (n < N_NODES) ? x[(size_t)n * IN_DIM + k] : 0.0f;
    }
    __syncthreads();
    float b = bp[c];
    float acc[NPB];
#pragma unroll
    for (int j = 0; j < NPB; j++) acc[j] = b;
    for (int k = 0; k < IN_DIM; k++) {
        float w = Wp[k * HID + c];
#pragma unroll
        for (int j = 0; j < NPB; j++) acc[j] += xs[j][k] * w;
    }
#pragma unroll
    for (int j = 0; j < NPB; j++) {
        int n = n0 + j;
        if (n < N_NODES) h[(size_t)n * HID + c] = acc[j];
    }
}

// ---------------- z = (1+eps[l]) * h -----------------------------------------
__global__ __launch_bounds__(256) void combine_kernel(
    const float* __restrict__ h, float* __restrict__ z,
    const float* __restrict__ eps, int layer) {
    float s = 1.0f + eps[layer];
    int i = blockIdx.x * blockDim.x + threadIdx.x;  // float4 index
    const int total = N_NODES * HID / 4;
    if (i < total) {
        float4 v = ((const float4*)h)[i];
        v.x *= s; v.y *= s; v.z *= s; v.w *= s;
        ((float4*)z)[i] = v;
    }
}

// ---------------- scatter: z[dst] += h[src] over edges -----------------------
// one wave (64 lanes) per edge, each lane a float4 (4 channels)
__global__ __launch_bounds__(256) void scatter_kernel(
    const int* __restrict__ ei, const float* __restrict__ h,
    float* __restrict__ z) {
    int e = blockIdx.x * 4 + (threadIdx.x >> 6);
    if (e >= N_EDGES) return;
    int lane = threadIdx.x & 63;
    int src = ei[e];
    int dst = ei[N_EDGES + e];
    float4 v = *(const float4*)&h[(size_t)src * HID + lane * 4];
    float* zp = &z[(size_t)dst * HID + lane * 4];
    atomicAdd(zp + 0, v.x);
    atomicAdd(zp + 1, v.y);
    atomicAdd(zp + 2, v.z);
    atomicAdd(zp + 3, v.w);
}

// ---------------- fp32 GEMM: C = [relu](A @ W + bias), A[M,256] W[256,256] ---
// BM=128 BN=128 BK=16, 256 threads, 8x8 per thread (split 4+4 to dodge
// LDS bank conflicts: each thread owns rows {ty*4..+3, 64+ty*4..+3} and
// cols {tx*4..+3, 64+tx*4..+3}).
#define BM 128
#define BN 128
#define BK 16
__global__ __launch_bounds__(256) void gemm256_kernel(
    const float* __restrict__ A, const float* __restrict__ W,
    const float* __restrict__ bias, float* __restrict__ C,
    int M, int doRelu) {
    __shared__ float As[BK][BM];
    __shared__ float Bs[BK][BN];
    int tid = threadIdx.x;
    int tx = tid & 15;
    int ty = tid >> 4;
    int m0 = blockIdx.x * BM;
    int n0 = blockIdx.y * BN;

    float acc[8][8];
#pragma unroll
    for (int i = 0; i < 8; i++)
#pragma unroll
        for (int j = 0; j < 8; j++) acc[i][j] = 0.0f;

    // A-load: q in {tid, tid+256}: r=q/4 (0..127), k4=q%4 -> 16 consecutive k
    int ar = tid >> 2;        // 0..63
    int ak4 = tid & 3;        // 0..3
    // B-load: q in {tid, tid+256}: rb=q/32 (0..15), cb=(q%32)*4
    int brow = tid >> 5;      // 0..7
    int bcol = (tid & 31) << 2;

    for (int kk = 0; kk < HID; kk += BK) {
#pragma unroll
        for (int half = 0; half < 2; half++) {
            int r = ar + half * 64;
            int m = m0 + r;
            float4 v = make_float4(0.f, 0.f, 0.f, 0.f);
            if (m < M) v = *(const float4*)&A[(size_t)m * HID + kk + ak4 * 4];
            As[ak4 * 4 + 0][r] = v.x;
            As[ak4 * 4 + 1][r] = v.y;
            As[ak4 * 4 + 2][r] = v.z;
            As[ak4 * 4 + 3][r] = v.w;
        }
#pragma unroll
        for (int half = 0; half < 2; half++) {
            int rb = brow + half * 8;
            *(float4*)&Bs[rb][bcol] =
                *(const float4*)&W[(size_t)(kk + rb) * HID + n0 + bcol];
        }
        __syncthreads();
#pragma unroll
        for (int k = 0; k < BK; k++) {
            float4 a0 = *(const float4*)&As[k][ty * 4];
            float4 a1 = *(const float4*)&As[k][64 + ty * 4];
            float4 b0 = *(const float4*)&Bs[k][tx * 4];
            float4 b1 = *(const float4*)&Bs[k][64 + tx * 4];
            float a[8] = {a0.x, a0.y, a0.z, a0.w, a1.x, a1.y, a1.z, a1.w};
            float b[8] = {b0.x, b0.y, b0.z, b0.w, b1.x, b1.y, b1.z, b1.w};
#pragma unroll
            for (int i = 0; i < 8; i++)
#pragma unroll
                for (int j = 0; j < 8; j++) acc[i][j] += a[i] * b[j];
        }
        __syncthreads();
    }

    float4 bia0 = *(const float4*)&bias[n0 + tx * 4];
    float4 bia1 = *(const float4*)&bias[n0 + 64 + tx * 4];
    float bi[8] = {bia0.x, bia0.y, bia0.z, bia0.w, bia1.x, bia1.y, bia1.z, bia1.w};
#pragma unroll
    for (int i = 0; i < 8; i++) {
        int r = (i < 4) ? (ty * 4 + i) : (64 + ty * 4 + (i - 4));
        int m = m0 + r;
        if (m >= M) continue;
        float4 o0, o1;
        float v;
        v = acc[i][0] + bi[0]; o0.x = doRelu ? fmaxf(v, 0.f) : v;
        v = acc[i][1] + bi[1]; o0.y = doRelu ? fmaxf(v, 0.f) : v;
        v = acc[i][2] + bi[2]; o0.z = doRelu ? fmaxf(v, 0.f) : v;
        v = acc[i][3] + bi[3]; o0.w = doRelu ? fmaxf(v, 0.f) : v;
        v = acc[i][4] + bi[4]; o1.x = doRelu ? fmaxf(v, 0.f) : v;
        v = acc[i][5] + bi[5]; o1.y = doRelu ? fmaxf(v, 0.f) : v;
        v = acc[i][6] + bi[6]; o1.z = doRelu ? fmaxf(v, 0.f) : v;
        v = acc[i][7] + bi[7]; o1.w = doRelu ? fmaxf(v, 0.f) : v;
        *(float4*)&C[(size_t)m * HID + n0 + tx * 4] = o0;
        *(float4*)&C[(size_t)m * HID + n0 + 64 + tx * 4] = o1;
    }
}

// ---------------- BN stats: column sums / sumsq ------------------------------
__global__ __launch_bounds__(256) void stats_kernel(
    const float* __restrict__ z, float* __restrict__ sums,
    float* __restrict__ sumsq) {
    int c = threadIdx.x;
    float s = 0.f, sq = 0.f;
    for (int r = blockIdx.x; r < N_NODES; r += gridDim.x) {
        float v = z[(size_t)r * HID + c];
        s += v;
        sq += v * v;
    }
    atomicAdd(&sums[c], s);
    atomicAdd(&sumsq[c], sq);
}

__global__ void bnparams_kernel(const float* __restrict__ sums,
                                const float* __restrict__ sumsq,
                                const float* __restrict__ gammas,
                                const float* __restrict__ betas, int layer,
                                float* __restrict__ scale,
                                float* __restrict__ shift) {
    int c = threadIdx.x;
    float mu = sums[c] / (float)N_NODES;
    float var = sumsq[c] / (float)N_NODES - mu * mu;
    float rs = rsqrtf(var + BN_EPS);
    float g = gammas[layer * HID + c];
    scale[c] = rs * g;
    shift[c] = betas[layer * HID + c] - mu * rs * g;
}

// ---------------- h = relu(z * scale + shift) --------------------------------
__global__ __launch_bounds__(256) void bnrelu_kernel(
    const float* __restrict__ z, const float* __restrict__ scale,
    const float* __restrict__ shift, float* __restrict__ h) {
    int i = blockIdx.x * blockDim.x + threadIdx.x;  // float4 index
    const int total = N_NODES * HID / 4;
    if (i >= total) return;
    int c4 = i & 63;  // 64 float4 per row
    float4 v = ((const float4*)z)[i];
    float4 sc = ((const float4*)scale)[c4];
    float4 sh = ((const float4*)shift)[c4];
    v.x = fmaxf(v.x * sc.x + sh.x, 0.f);
    v.y = fmaxf(v.y * sc.y + sh.y, 0.f);
    v.z = fmaxf(v.z * sc.z + sh.z, 0.f);
    v.w = fmaxf(v.w * sc.w + sh.w, 0.f);
    ((float4*)h)[i] = v;
}

// ---------------- pooling ----------------------------------------------------
__global__ __launch_bounds__(256) void count_kernel(const int* __restrict__ batch,
                                                    float* __restrict__ cnt) {
    int i = blockIdx.x * blockDim.x + threadIdx.x;
    if (i < N_NODES) atomicAdd(&cnt[batch[i]], 1.0f);
}

__global__ __launch_bounds__(256) void pool_kernel(
    const float* __restrict__ h, const int* __restrict__ batch,
    float* __restrict__ pool) {
    int idx = blockIdx.x * blockDim.x + threadIdx.x;  // over N_NODES*64
    int node = idx >> 6, q = idx & 63;
    if (node >= N_NODES) return;
    int b = batch[node];
    float4 v = *(const float4*)&h[(size_t)node * HID + q * 4];
    float* pp = &pool[(size_t)b * HID + q * 4];
    atomicAdd(pp + 0, v.x);
    atomicAdd(pp + 1, v.y);
    atomicAdd(pp + 2, v.z);
    atomicAdd(pp + 3, v.w);
}

// ---------------- readout: out[g] = relu(pooled@Wr1+br1)@Wr2 + br2 -----------
__global__ __launch_bounds__(256) void readout_kernel(
    const float* __restrict__ pool, const float* __restrict__ cnt,
    const float* __restrict__ Wr1, const float* __restrict__ br1,
    const float* __restrict__ Wr2, const float* __restrict__ br2,
    float* __restrict__ out) {
    __shared__ float p[HID];
    __shared__ float red[4];
    int g = blockIdx.x;
    int c = threadIdx.x;
    float inv = 1.0f / fmaxf(cnt[g], 1.0f);
    p[c] = pool[(size_t)g * HID + c] * inv;
    __syncthreads();
    float acc = br1[c];
    for (int k = 0; k < HID; k++) acc += p[k] * Wr1[k * HID + c];
    acc = fmaxf(acc, 0.f);
    float v = acc * Wr2[c];
#pragma unroll
    for (int off = 32; off > 0; off >>= 1) v += __shfl_down(v, off, 64);
    if ((c & 63) == 0) red[c >> 6] = v;
    __syncthreads();
    if (c == 0) out[g] = red[0] + red[1] + red[2] + red[3] + br2[0];
}

extern "C" void kernel_launch(void* const* d_in, const int* in_sizes, int n_in,
                              void* d_out, int out_size, void* d_ws, size_t ws_size,
                              hipStream_t stream) {
    const float* x      = (const float*)d_in[0];
    const int*   ei     = (const int*)d_in[1];
    const int*   batch  = (const int*)d_in[2];
    const float* Wp     = (const float*)d_in[3];
    const float* bp     = (const float*)d_in[4];
    const float* eps    = (const float*)d_in[5];
    const float* W1s    = (const float*)d_in[6];
    const float* b1s    = (const float*)d_in[7];
    const float* W2s    = (const float*)d_in[8];
    const float* b2s    = (const float*)d_in[9];
    const float* gammas = (const float*)d_in[10];
    const float* betas  = (const float*)d_in[11];
    const float* Wr1    = (const float*)d_in[12];
    const float* br1    = (const float*)d_in[13];
    const float* Wr2    = (const float*)d_in[14];
    const float* br2    = (const float*)d_in[15];
    float* out = (float*)d_out;

    const size_t NH = (size_t)N_NODES * HID;  // 25.6M floats
    float* h     = (float*)d_ws;
    float* z     = h + NH;
    float* sums  = z + NH;
    float* sumsq = sums + HID;
    float* scale = sumsq + HID;
    float* shift = scale + HID;
    float* pool  = shift + HID;
    float* cnt   = pool + (size_t)N_GRAPHS * HID;

    const int ELT4_BLOCKS = (N_NODES * HID / 4 + 255) / 256;  // 25000

    // h = x @ Wp + bp
    proj_kernel<<<(N_NODES + NPB - 1) / NPB, 256, 0, stream>>>(x, Wp, bp, h);

    for (int l = 0; l < LAYERS; l++) {
        combine_kernel<<<ELT4_BLOCKS, 256, 0, stream>>>(h, z, eps, l);
        scatter_kernel<<<(N_EDGES + 3) / 4, 256, 0, stream>>>(ei, h, z);
        // h = relu(z @ W1 + b1)
        gemm256_kernel<<<dim3((N_NODES + BM - 1) / BM, HID / BN), 256, 0, stream>>>(
            z, W1s + (size_t)l * HID * HID, b1s + l * HID, h, N_NODES, 1);
        // z = h @ W2 + b2
        gemm256_kernel<<<dim3((N_NODES + BM - 1) / BM, HID / BN), 256, 0, stream>>>(
            h, W2s + (size_t)l * HID * HID, b2s + l * HID, z, N_NODES, 0);
        hipMemsetAsync(sums, 0, 2 * HID * sizeof(float), stream);
        stats_kernel<<<2000, 256, 0, stream>>>(z, sums, sumsq);
        bnparams_kernel<<<1, HID, 0, stream>>>(sums, sumsq, gammas, betas, l,
                                               scale, shift);
        bnrelu_kernel<<<ELT4_BLOCKS, 256, 0, stream>>>(z, scale, shift, h);
    }

    // pooling + readout
    hipMemsetAsync(pool, 0, ((size_t)N_GRAPHS * HID + N_GRAPHS) * sizeof(float),
                   stream);
    count_kernel<<<(N_NODES + 255) / 256, 256, 0, stream>>>(batch, cnt);
    pool_kernel<<<(N_NODES * 64 + 255) / 256, 256, 0, stream>>>(h, batch, pool);
    readout_kernel<<<N_GRAPHS, 256, 0, stream>>>(pool, cnt, Wr1, br1, Wr2, br2,
                                                 out);
}

// Round 2
// 3105.784 us; speedup vs baseline: 2.5245x; 2.5245x over previous
//
#include <hip/hip_runtime.h>

#define N_NODES 100000
#define N_EDGES 300000
#define N_GRAPHS 2048
#define IN_DIM 38
#define HID 256
#define LAYERS 5
#define BN_EPS 1e-5f

#define SCAN_CHUNK 512
#define N_CHUNKS ((N_NODES + SCAN_CHUNK - 1) / SCAN_CHUNK)  // 196

// ---------------- projection: h = x @ Wp + bp  ([N,38]@[38,256]) -------------
#define NPB 4
__global__ __launch_bounds__(256) void proj_kernel(
    const float* __restrict__ x, const float* __restrict__ Wp,
    const float* __restrict__ bp, float* __restrict__ h) {
    __shared__ float xs[NPB][IN_DIM];
    int c = threadIdx.x;
    int n0 = blockIdx.x * NPB;
    for (int i = threadIdx.x; i < NPB * IN_DIM; i += 256) {
        int j = i / IN_DIM, k = i % IN_DIM;
        int n = n0 + j;
        xs[j][k] = (n < N_NODES) ? x[(size_t)n * IN_DIM + k] : 0.0f;
    }
    __syncthreads();
    float b = bp[c];
    float acc[NPB];
#pragma unroll
    for (int j = 0; j < NPB; j++) acc[j] = b;
    for (int k = 0; k < IN_DIM; k++) {
        float w = Wp[k * HID + c];
#pragma unroll
        for (int j = 0; j < NPB; j++) acc[j] += xs[j][k] * w;
    }
#pragma unroll
    for (int j = 0; j < NPB; j++) {
        int n = n0 + j;
        if (n < N_NODES) h[(size_t)n * HID + c] = acc[j];
    }
}

// ---------------- CSR build --------------------------------------------------
__global__ __launch_bounds__(256) void hist_kernel(const int* __restrict__ ei,
                                                   int* __restrict__ deg) {
    int e = blockIdx.x * 256 + threadIdx.x;
    if (e < N_EDGES) atomicAdd(&deg[ei[N_EDGES + e]], 1);
}

// per-chunk exclusive scan of deg -> offs, chunk totals -> blocksums
__global__ __launch_bounds__(256) void scan1_kernel(const int* __restrict__ deg,
                                                    int* __restrict__ offs,
                                                    int* __restrict__ blocksums) {
    __shared__ int s[SCAN_CHUNK];
    int base = blockIdx.x * SCAN_CHUNK;
    int t = threadIdx.x;
    int i0 = t, i1 = t + 256;
    int g0 = base + i0, g1 = base + i1;
    int o0 = (g0 < N_NODES) ? deg[g0] : 0;
    int o1 = (g1 < N_NODES) ? deg[g1] : 0;
    s[i0] = o0;
    s[i1] = o1;
    __syncthreads();
    for (int off = 1; off < SCAN_CHUNK; off <<= 1) {
        int v0 = (i0 >= off) ? s[i0 - off] : 0;
        int v1 = (i1 >= off) ? s[i1 - off] : 0;
        __syncthreads();
        s[i0] += v0;
        s[i1] += v1;
        __syncthreads();
    }
    if (g0 < N_NODES) offs[g0] = s[i0] - o0;
    if (g1 < N_NODES) offs[g1] = s[i1] - o1;
    if (t == 0) blocksums[blockIdx.x] = s[SCAN_CHUNK - 1];
}

// exclusive scan of blocksums in place (N_CHUNKS <= 256)
__global__ __launch_bounds__(256) void scan2_kernel(int* __restrict__ blocksums) {
    __shared__ int s[256];
    int t = threadIdx.x;
    int o = (t < N_CHUNKS) ? blocksums[t] : 0;
    s[t] = o;
    __syncthreads();
    for (int off = 1; off < 256; off <<= 1) {
        int v = (t >= off) ? s[t - off] : 0;
        __syncthreads();
        s[t] += v;
        __syncthreads();
    }
    if (t < N_CHUNKS) blocksums[t] = s[t] - o;
}

// add chunk offsets; also copy to cursor and set offs[N_NODES]
__global__ __launch_bounds__(256) void scan3_kernel(int* __restrict__ offs,
                                                    const int* __restrict__ blocksums,
                                                    int* __restrict__ cursor) {
    int g = blockIdx.x * 256 + threadIdx.x;
    if (g < N_NODES) {
        int v = offs[g] + blocksums[g / SCAN_CHUNK];
        offs[g] = v;
        cursor[g] = v;
    }
    if (g == 0) offs[N_NODES] = N_EDGES;
}

__global__ __launch_bounds__(256) void fill_kernel(const int* __restrict__ ei,
                                                   int* __restrict__ cursor,
                                                   int* __restrict__ csr_src) {
    int e = blockIdx.x * 256 + threadIdx.x;
    if (e < N_EDGES) {
        int src = ei[e];
        int dst = ei[N_EDGES + e];
        int pos = atomicAdd(&cursor[dst], 1);
        csr_src[pos] = src;
    }
}

// ---------------- gather: z[i] = (1+eps)*h[i] + sum_{j->i} h[j] --------------
// one wave per node; lane l owns channels [4l, 4l+4)
__global__ __launch_bounds__(256) void gather_kernel(
    const int* __restrict__ offs, const int* __restrict__ csr_src,
    const float* __restrict__ h, float* __restrict__ z,
    const float* __restrict__ eps, int layer) {
    int wave = threadIdx.x >> 6;
    int lane = threadIdx.x & 63;
    int node = blockIdx.x * 4 + wave;
    if (node >= N_NODES) return;
    float s = 1.0f + eps[layer];
    int beg = offs[node], end = offs[node + 1];
    float4 acc = *(const float4*)&h[(size_t)node * HID + lane * 4];
    acc.x *= s; acc.y *= s; acc.z *= s; acc.w *= s;
    for (int e = beg; e < end; e++) {
        int src = csr_src[e];
        float4 v = *(const float4*)&h[(size_t)src * HID + lane * 4];
        acc.x += v.x; acc.y += v.y; acc.z += v.z; acc.w += v.w;
    }
    *(float4*)&z[(size_t)node * HID + lane * 4] = acc;
}

// ---------------- fp32 GEMM: C = [relu](A @ W + bias), A[M,256] W[256,256] ---
#define BM 128
#define BN 128
#define BK 16
__global__ __launch_bounds__(256) void gemm256_kernel(
    const float* __restrict__ A, const float* __restrict__ W,
    const float* __restrict__ bias, float* __restrict__ C,
    int M, int doRelu) {
    __shared__ float As[BK][BM];
    __shared__ float Bs[BK][BN];
    int tid = threadIdx.x;
    int tx = tid & 15;
    int ty = tid >> 4;
    int m0 = blockIdx.x * BM;
    int n0 = blockIdx.y * BN;

    float acc[8][8];
#pragma unroll
    for (int i = 0; i < 8; i++)
#pragma unroll
        for (int j = 0; j < 8; j++) acc[i][j] = 0.0f;

    int ar = tid >> 2;
    int ak4 = tid & 3;
    int brow = tid >> 5;
    int bcol = (tid & 31) << 2;

    for (int kk = 0; kk < HID; kk += BK) {
#pragma unroll
        for (int half = 0; half < 2; half++) {
            int r = ar + half * 64;
            int m = m0 + r;
            float4 v = make_float4(0.f, 0.f, 0.f, 0.f);
            if (m < M) v = *(const float4*)&A[(size_t)m * HID + kk + ak4 * 4];
            As[ak4 * 4 + 0][r] = v.x;
            As[ak4 * 4 + 1][r] = v.y;
            As[ak4 * 4 + 2][r] = v.z;
            As[ak4 * 4 + 3][r] = v.w;
        }
#pragma unroll
        for (int half = 0; half < 2; half++) {
            int rb = brow + half * 8;
            *(float4*)&Bs[rb][bcol] =
                *(const float4*)&W[(size_t)(kk + rb) * HID + n0 + bcol];
        }
        __syncthreads();
#pragma unroll
        for (int k = 0; k < BK; k++) {
            float4 a0 = *(const float4*)&As[k][ty * 4];
            float4 a1 = *(const float4*)&As[k][64 + ty * 4];
            float4 b0 = *(const float4*)&Bs[k][tx * 4];
            float4 b1 = *(const float4*)&Bs[k][64 + tx * 4];
            float a[8] = {a0.x, a0.y, a0.z, a0.w, a1.x, a1.y, a1.z, a1.w};
            float b[8] = {b0.x, b0.y, b0.z, b0.w, b1.x, b1.y, b1.z, b1.w};
#pragma unroll
            for (int i = 0; i < 8; i++)
#pragma unroll
                for (int j = 0; j < 8; j++) acc[i][j] += a[i] * b[j];
        }
        __syncthreads();
    }

    float4 bia0 = *(const float4*)&bias[n0 + tx * 4];
    float4 bia1 = *(const float4*)&bias[n0 + 64 + tx * 4];
    float bi[8] = {bia0.x, bia0.y, bia0.z, bia0.w, bia1.x, bia1.y, bia1.z, bia1.w};
#pragma unroll
    for (int i = 0; i < 8; i++) {
        int r = (i < 4) ? (ty * 4 + i) : (64 + ty * 4 + (i - 4));
        int m = m0 + r;
        if (m >= M) continue;
        float4 o0, o1;
        float v;
        v = acc[i][0] + bi[0]; o0.x = doRelu ? fmaxf(v, 0.f) : v;
        v = acc[i][1] + bi[1]; o0.y = doRelu ? fmaxf(v, 0.f) : v;
        v = acc[i][2] + bi[2]; o0.z = doRelu ? fmaxf(v, 0.f) : v;
        v = acc[i][3] + bi[3]; o0.w = doRelu ? fmaxf(v, 0.f) : v;
        v = acc[i][4] + bi[4]; o1.x = doRelu ? fmaxf(v, 0.f) : v;
        v = acc[i][5] + bi[5]; o1.y = doRelu ? fmaxf(v, 0.f) : v;
        v = acc[i][6] + bi[6]; o1.z = doRelu ? fmaxf(v, 0.f) : v;
        v = acc[i][7] + bi[7]; o1.w = doRelu ? fmaxf(v, 0.f) : v;
        *(float4*)&C[(size_t)m * HID + n0 + tx * 4] = o0;
        *(float4*)&C[(size_t)m * HID + n0 + 64 + tx * 4] = o1;
    }
}

// ---------------- BN stats: column sums / sumsq ------------------------------
__global__ __launch_bounds__(256) void stats_kernel(
    const float* __restrict__ z, float* __restrict__ sums,
    float* __restrict__ sumsq) {
    int c = threadIdx.x;
    float s = 0.f, sq = 0.f;
    for (int r = blockIdx.x; r < N_NODES; r += gridDim.x) {
        float v = z[(size_t)r * HID + c];
        s += v;
        sq += v * v;
    }
    atomicAdd(&sums[c], s);
    atomicAdd(&sumsq[c], sq);
}

__global__ void bnparams_kernel(const float* __restrict__ sums,
                                const float* __restrict__ sumsq,
                                const float* __restrict__ gammas,
                                const float* __restrict__ betas, int layer,
                                float* __restrict__ scale,
                                float* __restrict__ shift) {
    int c = threadIdx.x;
    float mu = sums[c] / (float)N_NODES;
    float var = sumsq[c] / (float)N_NODES - mu * mu;
    float rs = rsqrtf(var + BN_EPS);
    float g = gammas[layer * HID + c];
    scale[c] = rs * g;
    shift[c] = betas[layer * HID + c] - mu * rs * g;
}

// ---------------- h = relu(z * scale + shift) --------------------------------
__global__ __launch_bounds__(256) void bnrelu_kernel(
    const float* __restrict__ z, const float* __restrict__ scale,
    const float* __restrict__ shift, float* __restrict__ h) {
    int i = blockIdx.x * blockDim.x + threadIdx.x;  // float4 index
    const int total = N_NODES * HID / 4;
    if (i >= total) return;
    int c4 = i & 63;
    float4 v = ((const float4*)z)[i];
    float4 sc = ((const float4*)scale)[c4];
    float4 sh = ((const float4*)shift)[c4];
    v.x = fmaxf(v.x * sc.x + sh.x, 0.f);
    v.y = fmaxf(v.y * sc.y + sh.y, 0.f);
    v.z = fmaxf(v.z * sc.z + sh.z, 0.f);
    v.w = fmaxf(v.w * sc.w + sh.w, 0.f);
    ((float4*)h)[i] = v;
}

// ---------------- pooling ----------------------------------------------------
__global__ __launch_bounds__(256) void count_kernel(const int* __restrict__ batch,
                                                    float* __restrict__ cnt) {
    int i = blockIdx.x * blockDim.x + threadIdx.x;
    if (i < N_NODES) atomicAdd(&cnt[batch[i]], 1.0f);
}

__global__ __launch_bounds__(256) void pool_kernel(
    const float* __restrict__ h, const int* __restrict__ batch,
    float* __restrict__ pool) {
    int idx = blockIdx.x * blockDim.x + threadIdx.x;
    int node = idx >> 6, q = idx & 63;
    if (node >= N_NODES) return;
    int b = batch[node];
    float4 v = *(const float4*)&h[(size_t)node * HID + q * 4];
    float* pp = &pool[(size_t)b * HID + q * 4];
    atomicAdd(pp + 0, v.x);
    atomicAdd(pp + 1, v.y);
    atomicAdd(pp + 2, v.z);
    atomicAdd(pp + 3, v.w);
}

// ---------------- readout ----------------------------------------------------
__global__ __launch_bounds__(256) void readout_kernel(
    const float* __restrict__ pool, const float* __restrict__ cnt,
    const float* __restrict__ Wr1, const float* __restrict__ br1,
    const float* __restrict__ Wr2, const float* __restrict__ br2,
    float* __restrict__ out) {
    __shared__ float p[HID];
    __shared__ float red[4];
    int g = blockIdx.x;
    int c = threadIdx.x;
    float inv = 1.0f / fmaxf(cnt[g], 1.0f);
    p[c] = pool[(size_t)g * HID + c] * inv;
    __syncthreads();
    float acc = br1[c];
    for (int k = 0; k < HID; k++) acc += p[k] * Wr1[k * HID + c];
    acc = fmaxf(acc, 0.f);
    float v = acc * Wr2[c];
#pragma unroll
    for (int off = 32; off > 0; off >>= 1) v += __shfl_down(v, off, 64);
    if ((c & 63) == 0) red[c >> 6] = v;
    __syncthreads();
    if (c == 0) out[g] = red[0] + red[1] + red[2] + red[3] + br2[0];
}

extern "C" void kernel_launch(void* const* d_in, const int* in_sizes, int n_in,
                              void* d_out, int out_size, void* d_ws, size_t ws_size,
                              hipStream_t stream) {
    const float* x      = (const float*)d_in[0];
    const int*   ei     = (const int*)d_in[1];
    const int*   batch  = (const int*)d_in[2];
    const float* Wp     = (const float*)d_in[3];
    const float* bp     = (const float*)d_in[4];
    const float* eps    = (const float*)d_in[5];
    const float* W1s    = (const float*)d_in[6];
    const float* b1s    = (const float*)d_in[7];
    const float* W2s    = (const float*)d_in[8];
    const float* b2s    = (const float*)d_in[9];
    const float* gammas = (const float*)d_in[10];
    const float* betas  = (const float*)d_in[11];
    const float* Wr1    = (const float*)d_in[12];
    const float* br1    = (const float*)d_in[13];
    const float* Wr2    = (const float*)d_in[14];
    const float* br2    = (const float*)d_in[15];
    float* out = (float*)d_out;

    const size_t NH = (size_t)N_NODES * HID;
    float* h     = (float*)d_ws;
    float* z     = h + NH;
    float* sums  = z + NH;
    float* sumsq = sums + HID;
    float* scale = sumsq + HID;
    float* shift = scale + HID;
    float* pool  = shift + HID;
    float* cnt   = pool + (size_t)N_GRAPHS * HID;
    int* deg       = (int*)(cnt + N_GRAPHS);
    int* offs      = deg + N_NODES;        // N_NODES+1
    int* cursor    = offs + N_NODES + 1;
    int* csr_src   = cursor + N_NODES;
    int* blocksums = csr_src + N_EDGES;    // N_CHUNKS

    const int ELT4_BLOCKS = (N_NODES * HID / 4 + 255) / 256;

    // ---- CSR build (once per launch) ----
    hipMemsetAsync(deg, 0, N_NODES * sizeof(int), stream);
    hist_kernel<<<(N_EDGES + 255) / 256, 256, 0, stream>>>(ei, deg);
    scan1_kernel<<<N_CHUNKS, 256, 0, stream>>>(deg, offs, blocksums);
    scan2_kernel<<<1, 256, 0, stream>>>(blocksums);
    scan3_kernel<<<(N_NODES + 255) / 256, 256, 0, stream>>>(offs, blocksums,
                                                            cursor);
    fill_kernel<<<(N_EDGES + 255) / 256, 256, 0, stream>>>(ei, cursor, csr_src);

    // h = x @ Wp + bp
    proj_kernel<<<(N_NODES + NPB - 1) / NPB, 256, 0, stream>>>(x, Wp, bp, h);

    for (int l = 0; l < LAYERS; l++) {
        gather_kernel<<<(N_NODES + 3) / 4, 256, 0, stream>>>(offs, csr_src, h, z,
                                                             eps, l);
        gemm256_kernel<<<dim3((N_NODES + BM - 1) / BM, HID / BN), 256, 0, stream>>>(
            z, W1s + (size_t)l * HID * HID, b1s + l * HID, h, N_NODES, 1);
        gemm256_kernel<<<dim3((N_NODES + BM - 1) / BM, HID / BN), 256, 0, stream>>>(
            h, W2s + (size_t)l * HID * HID, b2s + l * HID, z, N_NODES, 0);
        hipMemsetAsync(sums, 0, 2 * HID * sizeof(float), stream);
        stats_kernel<<<2000, 256, 0, stream>>>(z, sums, sumsq);
        bnparams_kernel<<<1, HID, 0, stream>>>(sums, sumsq, gammas, betas, l,
                                               scale, shift);
        bnrelu_kernel<<<ELT4_BLOCKS, 256, 0, stream>>>(z, scale, shift, h);
    }

    hipMemsetAsync(pool, 0, ((size_t)N_GRAPHS * HID + N_GRAPHS) * sizeof(float),
                   stream);
    count_kernel<<<(N_NODES + 255) / 256, 256, 0, stream>>>(batch, cnt);
    pool_kernel<<<(N_NODES * 64 + 255) / 256, 256, 0, stream>>>(h, batch, pool);
    readout_kernel<<<N_GRAPHS, 256, 0, stream>>>(pool, cnt, Wr1, br1, Wr2, br2,
                                                 out);
}

// Round 3
// 2761.836 us; speedup vs baseline: 2.8389x; 1.1245x over previous
//
#include <hip/hip_runtime.h>

#define N_NODES 100000
#define N_EDGES 300000
#define N_GRAPHS 2048
#define IN_DIM 38
#define HID 256
#define LAYERS 5
#define BN_EPS 1e-5f

#define SCAN_CHUNK 512
#define N_CHUNKS ((N_NODES + SCAN_CHUNK - 1) / SCAN_CHUNK)  // 196

// ---------------- projection: h = x @ Wp + bp  ([N,38]@[38,256]) -------------
#define NPB 4
__global__ __launch_bounds__(256) void proj_kernel(
    const float* __restrict__ x, const float* __restrict__ Wp,
    const float* __restrict__ bp, float* __restrict__ h) {
    __shared__ float xs[NPB][IN_DIM];
    int c = threadIdx.x;
    int n0 = blockIdx.x * NPB;
    for (int i = threadIdx.x; i < NPB * IN_DIM; i += 256) {
        int j = i / IN_DIM, k = i % IN_DIM;
        int n = n0 + j;
        xs[j][k] = (n < N_NODES) ? x[(size_t)n * IN_DIM + k] : 0.0f;
    }
    __syncthreads();
    float b = bp[c];
    float acc[NPB];
#pragma unroll
    for (int j = 0; j < NPB; j++) acc[j] = b;
    for (int k = 0; k < IN_DIM; k++) {
        float w = Wp[k * HID + c];
#pragma unroll
        for (int j = 0; j < NPB; j++) acc[j] += xs[j][k] * w;
    }
#pragma unroll
    for (int j = 0; j < NPB; j++) {
        int n = n0 + j;
        if (n < N_NODES) h[(size_t)n * HID + c] = acc[j];
    }
}

// ---------------- CSR build --------------------------------------------------
__global__ __launch_bounds__(256) void hist_kernel(const int* __restrict__ ei,
                                                   int* __restrict__ deg) {
    int e = blockIdx.x * 256 + threadIdx.x;
    if (e < N_EDGES) atomicAdd(&deg[ei[N_EDGES + e]], 1);
}

__global__ __launch_bounds__(256) void scan1_kernel(const int* __restrict__ deg,
                                                    int* __restrict__ offs,
                                                    int* __restrict__ blocksums) {
    __shared__ int s[SCAN_CHUNK];
    int base = blockIdx.x * SCAN_CHUNK;
    int t = threadIdx.x;
    int i0 = t, i1 = t + 256;
    int g0 = base + i0, g1 = base + i1;
    int o0 = (g0 < N_NODES) ? deg[g0] : 0;
    int o1 = (g1 < N_NODES) ? deg[g1] : 0;
    s[i0] = o0;
    s[i1] = o1;
    __syncthreads();
    for (int off = 1; off < SCAN_CHUNK; off <<= 1) {
        int v0 = (i0 >= off) ? s[i0 - off] : 0;
        int v1 = (i1 >= off) ? s[i1 - off] : 0;
        __syncthreads();
        s[i0] += v0;
        s[i1] += v1;
        __syncthreads();
    }
    if (g0 < N_NODES) offs[g0] = s[i0] - o0;
    if (g1 < N_NODES) offs[g1] = s[i1] - o1;
    if (t == 0) blocksums[blockIdx.x] = s[SCAN_CHUNK - 1];
}

__global__ __launch_bounds__(256) void scan2_kernel(int* __restrict__ blocksums) {
    __shared__ int s[256];
    int t = threadIdx.x;
    int o = (t < N_CHUNKS) ? blocksums[t] : 0;
    s[t] = o;
    __syncthreads();
    for (int off = 1; off < 256; off <<= 1) {
        int v = (t >= off) ? s[t - off] : 0;
        __syncthreads();
        s[t] += v;
        __syncthreads();
    }
    if (t < N_CHUNKS) blocksums[t] = s[t] - o;
}

__global__ __launch_bounds__(256) void scan3_kernel(int* __restrict__ offs,
                                                    const int* __restrict__ blocksums,
                                                    int* __restrict__ cursor) {
    int g = blockIdx.x * 256 + threadIdx.x;
    if (g < N_NODES) {
        int v = offs[g] + blocksums[g / SCAN_CHUNK];
        offs[g] = v;
        cursor[g] = v;
    }
    if (g == 0) offs[N_NODES] = N_EDGES;
}

__global__ __launch_bounds__(256) void fill_kernel(const int* __restrict__ ei,
                                                   int* __restrict__ cursor,
                                                   int* __restrict__ csr_src) {
    int e = blockIdx.x * 256 + threadIdx.x;
    if (e < N_EDGES) {
        int src = ei[e];
        int dst = ei[N_EDGES + e];
        int pos = atomicAdd(&cursor[dst], 1);
        csr_src[pos] = src;
    }
}

// ---------------- gather: z[i] = (1+eps)*h[i] + sum_{j->i} h[j] --------------
__global__ __launch_bounds__(256) void gather_kernel(
    const int* __restrict__ offs, const int* __restrict__ csr_src,
    const float* __restrict__ h, float* __restrict__ z,
    const float* __restrict__ eps, int layer) {
    int wave = threadIdx.x >> 6;
    int lane = threadIdx.x & 63;
    int node = blockIdx.x * 4 + wave;
    if (node >= N_NODES) return;
    float s = 1.0f + eps[layer];
    int beg = offs[node], end = offs[node + 1];
    float4 acc = *(const float4*)&h[(size_t)node * HID + lane * 4];
    acc.x *= s; acc.y *= s; acc.z *= s; acc.w *= s;
    for (int e = beg; e < end; e++) {
        int src = csr_src[e];
        float4 v = *(const float4*)&h[(size_t)src * HID + lane * 4];
        acc.x += v.x; acc.y += v.y; acc.z += v.z; acc.w += v.w;
    }
    *(float4*)&z[(size_t)node * HID + lane * 4] = acc;
}

// ---------------- fp32 GEMM: C = [relu](A @ W + bias), A[M,256] W[256,256] ---
#define BM 128
#define BN 128
#define BK 16
__global__ __launch_bounds__(256) void gemm256_kernel(
    const float* __restrict__ A, const float* __restrict__ W,
    const float* __restrict__ bias, float* __restrict__ C,
    int M, int doRelu) {
    __shared__ float As[BK][BM];
    __shared__ float Bs[BK][BN];
    int tid = threadIdx.x;
    int tx = tid & 15;
    int ty = tid >> 4;
    int m0 = blockIdx.x * BM;
    int n0 = blockIdx.y * BN;

    float acc[8][8];
#pragma unroll
    for (int i = 0; i < 8; i++)
#pragma unroll
        for (int j = 0; j < 8; j++) acc[i][j] = 0.0f;

    int ar = tid >> 2;
    int ak4 = tid & 3;
    int brow = tid >> 5;
    int bcol = (tid & 31) << 2;

    for (int kk = 0; kk < HID; kk += BK) {
#pragma unroll
        for (int half = 0; half < 2; half++) {
            int r = ar + half * 64;
            int m = m0 + r;
            float4 v = make_float4(0.f, 0.f, 0.f, 0.f);
            if (m < M) v = *(const float4*)&A[(size_t)m * HID + kk + ak4 * 4];
            As[ak4 * 4 + 0][r] = v.x;
            As[ak4 * 4 + 1][r] = v.y;
            As[ak4 * 4 + 2][r] = v.z;
            As[ak4 * 4 + 3][r] = v.w;
        }
#pragma unroll
        for (int half = 0; half < 2; half++) {
            int rb = brow + half * 8;
            *(float4*)&Bs[rb][bcol] =
                *(const float4*)&W[(size_t)(kk + rb) * HID + n0 + bcol];
        }
        __syncthreads();
#pragma unroll
        for (int k = 0; k < BK; k++) {
            float4 a0 = *(const float4*)&As[k][ty * 4];
            float4 a1 = *(const float4*)&As[k][64 + ty * 4];
            float4 b0 = *(const float4*)&Bs[k][tx * 4];
            float4 b1 = *(const float4*)&Bs[k][64 + tx * 4];
            float a[8] = {a0.x, a0.y, a0.z, a0.w, a1.x, a1.y, a1.z, a1.w};
            float b[8] = {b0.x, b0.y, b0.z, b0.w, b1.x, b1.y, b1.z, b1.w};
#pragma unroll
            for (int i = 0; i < 8; i++)
#pragma unroll
                for (int j = 0; j < 8; j++) acc[i][j] += a[i] * b[j];
        }
        __syncthreads();
    }

    float4 bia0 = *(const float4*)&bias[n0 + tx * 4];
    float4 bia1 = *(const float4*)&bias[n0 + 64 + tx * 4];
    float bi[8] = {bia0.x, bia0.y, bia0.z, bia0.w, bia1.x, bia1.y, bia1.z, bia1.w};
#pragma unroll
    for (int i = 0; i < 8; i++) {
        int r = (i < 4) ? (ty * 4 + i) : (64 + ty * 4 + (i - 4));
        int m = m0 + r;
        if (m >= M) continue;
        float4 o0, o1;
        float v;
        v = acc[i][0] + bi[0]; o0.x = doRelu ? fmaxf(v, 0.f) : v;
        v = acc[i][1] + bi[1]; o0.y = doRelu ? fmaxf(v, 0.f) : v;
        v = acc[i][2] + bi[2]; o0.z = doRelu ? fmaxf(v, 0.f) : v;
        v = acc[i][3] + bi[3]; o0.w = doRelu ? fmaxf(v, 0.f) : v;
        v = acc[i][4] + bi[4]; o1.x = doRelu ? fmaxf(v, 0.f) : v;
        v = acc[i][5] + bi[5]; o1.y = doRelu ? fmaxf(v, 0.f) : v;
        v = acc[i][6] + bi[6]; o1.z = doRelu ? fmaxf(v, 0.f) : v;
        v = acc[i][7] + bi[7]; o1.w = doRelu ? fmaxf(v, 0.f) : v;
        *(float4*)&C[(size_t)m * HID + n0 + tx * 4] = o0;
        *(float4*)&C[(size_t)m * HID + n0 + 64 + tx * 4] = o1;
    }
}

// ---------------- BN stats: column sums / sumsq ------------------------------
__global__ __launch_bounds__(256) void stats_kernel(
    const float* __restrict__ z, float* __restrict__ sums,
    float* __restrict__ sumsq) {
    int c = threadIdx.x;
    float s = 0.f, sq = 0.f;
    for (int r = blockIdx.x; r < N_NODES; r += gridDim.x) {
        float v = z[(size_t)r * HID + c];
        s += v;
        sq += v * v;
    }
    atomicAdd(&sums[c], s);
    atomicAdd(&sumsq[c], sq);
}

__global__ void bnparams_kernel(const float* __restrict__ sums,
                                const float* __restrict__ sumsq,
                                const float* __restrict__ gammas,
                                const float* __restrict__ betas, int layer,
                                float* __restrict__ scale,
                                float* __restrict__ shift) {
    int c = threadIdx.x;
    float mu = sums[c] / (float)N_NODES;
    float var = sumsq[c] / (float)N_NODES - mu * mu;
    float rs = rsqrtf(var + BN_EPS);
    float g = gammas[layer * HID + c];
    scale[c] = rs * g;
    shift[c] = betas[layer * HID + c] - mu * rs * g;
}

// ---------------- h = relu(z * scale + shift) --------------------------------
__global__ __launch_bounds__(256) void bnrelu_kernel(
    const float* __restrict__ z, const float* __restrict__ scale,
    const float* __restrict__ shift, float* __restrict__ h) {
    int i = blockIdx.x * blockDim.x + threadIdx.x;  // float4 index
    const int total = N_NODES * HID / 4;
    if (i >= total) return;
    int c4 = i & 63;
    float4 v = ((const float4*)z)[i];
    float4 sc = ((const float4*)scale)[c4];
    float4 sh = ((const float4*)shift)[c4];
    v.x = fmaxf(v.x * sc.x + sh.x, 0.f);
    v.y = fmaxf(v.y * sc.y + sh.y, 0.f);
    v.z = fmaxf(v.z * sc.z + sh.z, 0.f);
    v.w = fmaxf(v.w * sc.w + sh.w, 0.f);
    ((float4*)h)[i] = v;
}

// ---------------- pooling (batch is sorted -> segmented reduction) -----------
// start[g] = lower_bound(batch, g), for g in [0, N_GRAPHS]
__global__ __launch_bounds__(256) void bounds_kernel(const int* __restrict__ batch,
                                                     int* __restrict__ start) {
    int g = blockIdx.x * 256 + threadIdx.x;
    if (g > N_GRAPHS) return;
    int lo = 0, hi = N_NODES;
    while (lo < hi) {
        int mid = (lo + hi) >> 1;
        if (batch[mid] < g) lo = mid + 1;
        else hi = mid;
    }
    start[g] = lo;
}

// one block per graph; thread c sums channel c over the graph's node range
__global__ __launch_bounds__(256) void segpool_kernel(
    const float* __restrict__ h, const int* __restrict__ start,
    float* __restrict__ pooled) {
    int g = blockIdx.x;
    int c = threadIdx.x;
    int beg = start[g], end = start[g + 1];
    float s = 0.f;
    for (int n = beg; n < end; n++) s += h[(size_t)n * HID + c];
    float inv = 1.0f / fmaxf((float)(end - beg), 1.0f);
    pooled[(size_t)g * HID + c] = s * inv;
}

// ---------------- readout: out[g] = relu(pooled@Wr1+br1)@Wr2 + br2 -----------
__global__ __launch_bounds__(256) void readout_kernel(
    const float* __restrict__ pooled, const float* __restrict__ Wr1,
    const float* __restrict__ br1, const float* __restrict__ Wr2,
    const float* __restrict__ br2, float* __restrict__ out) {
    __shared__ float p[HID];
    __shared__ float red[4];
    int g = blockIdx.x;
    int c = threadIdx.x;
    p[c] = pooled[(size_t)g * HID + c];
    __syncthreads();
    float acc = br1[c];
    for (int k = 0; k < HID; k++) acc += p[k] * Wr1[k * HID + c];
    acc = fmaxf(acc, 0.f);
    float v = acc * Wr2[c];
#pragma unroll
    for (int off = 32; off > 0; off >>= 1) v += __shfl_down(v, off, 64);
    if ((c & 63) == 0) red[c >> 6] = v;
    __syncthreads();
    if (c == 0) out[g] = red[0] + red[1] + red[2] + red[3] + br2[0];
}

extern "C" void kernel_launch(void* const* d_in, const int* in_sizes, int n_in,
                              void* d_out, int out_size, void* d_ws, size_t ws_size,
                              hipStream_t stream) {
    const float* x      = (const float*)d_in[0];
    const int*   ei     = (const int*)d_in[1];
    const int*   batch  = (const int*)d_in[2];
    const float* Wp     = (const float*)d_in[3];
    const float* bp     = (const float*)d_in[4];
    const float* eps    = (const float*)d_in[5];
    const float* W1s    = (const float*)d_in[6];
    const float* b1s    = (const float*)d_in[7];
    const float* W2s    = (const float*)d_in[8];
    const float* b2s    = (const float*)d_in[9];
    const float* gammas = (const float*)d_in[10];
    const float* betas  = (const float*)d_in[11];
    const float* Wr1    = (const float*)d_in[12];
    const float* br1    = (const float*)d_in[13];
    const float* Wr2    = (const float*)d_in[14];
    const float* br2    = (const float*)d_in[15];
    float* out = (float*)d_out;

    const size_t NH = (size_t)N_NODES * HID;
    float* h      = (float*)d_ws;
    float* z      = h + NH;
    float* sums   = z + NH;
    float* sumsq  = sums + HID;
    float* scale  = sumsq + HID;
    float* shift  = scale + HID;
    float* pooled = shift + HID;
    int* start     = (int*)(pooled + (size_t)N_GRAPHS * HID);  // N_GRAPHS+1
    int* deg       = start + N_GRAPHS + 1;
    int* offs      = deg + N_NODES;        // N_NODES+1
    int* cursor    = offs + N_NODES + 1;
    int* csr_src   = cursor + N_NODES;
    int* blocksums = csr_src + N_EDGES;    // N_CHUNKS

    const int ELT4_BLOCKS = (N_NODES * HID / 4 + 255) / 256;

    // ---- CSR build (once per launch) ----
    hipMemsetAsync(deg, 0, N_NODES * sizeof(int), stream);
    hist_kernel<<<(N_EDGES + 255) / 256, 256, 0, stream>>>(ei, deg);
    scan1_kernel<<<N_CHUNKS, 256, 0, stream>>>(deg, offs, blocksums);
    scan2_kernel<<<1, 256, 0, stream>>>(blocksums);
    scan3_kernel<<<(N_NODES + 255) / 256, 256, 0, stream>>>(offs, blocksums,
                                                            cursor);
    fill_kernel<<<(N_EDGES + 255) / 256, 256, 0, stream>>>(ei, cursor, csr_src);

    // graph segment bounds from sorted batch
    bounds_kernel<<<(N_GRAPHS + 1 + 255) / 256, 256, 0, stream>>>(batch, start);

    // h = x @ Wp + bp
    proj_kernel<<<(N_NODES + NPB - 1) / NPB, 256, 0, stream>>>(x, Wp, bp, h);

    for (int l = 0; l < LAYERS; l++) {
        gather_kernel<<<(N_NODES + 3) / 4, 256, 0, stream>>>(offs, csr_src, h, z,
                                                             eps, l);
        gemm256_kernel<<<dim3((N_NODES + BM - 1) / BM, HID / BN), 256, 0, stream>>>(
            z, W1s + (size_t)l * HID * HID, b1s + l * HID, h, N_NODES, 1);
        gemm256_kernel<<<dim3((N_NODES + BM - 1) / BM, HID / BN), 256, 0, stream>>>(
            h, W2s + (size_t)l * HID * HID, b2s + l * HID, z, N_NODES, 0);
        hipMemsetAsync(sums, 0, 2 * HID * sizeof(float), stream);
        stats_kernel<<<2000, 256, 0, stream>>>(z, sums, sumsq);
        bnparams_kernel<<<1, HID, 0, stream>>>(sums, sumsq, gammas, betas, l,
                                               scale, shift);
        bnrelu_kernel<<<ELT4_BLOCKS, 256, 0, stream>>>(z, scale, shift, h);
    }

    segpool_kernel<<<N_GRAPHS, 256, 0, stream>>>(h, start, pooled);
    readout_kernel<<<N_GRAPHS, 256, 0, stream>>>(pooled, Wr1, br1, Wr2, br2, out);
}

// Round 4
// 2080.472 us; speedup vs baseline: 3.7686x; 1.3275x over previous
//
#include <hip/hip_runtime.h>

#define N_NODES 100000
#define N_EDGES 300000
#define N_GRAPHS 2048
#define IN_DIM 38
#define HID 256
#define LAYERS 5
#define BN_EPS 1e-5f

#define SCAN_CHUNK 512
#define N_CHUNKS ((N_NODES + SCAN_CHUNK - 1) / SCAN_CHUNK)  // 196

typedef __attribute__((ext_vector_type(8))) short short8;   // 8 bf16 = 4 VGPR
typedef __attribute__((ext_vector_type(4))) float floatx4;  // MFMA acc

__device__ inline unsigned short bf16_rne(float f) {
    unsigned int u = __float_as_uint(f);
    unsigned int r = (u + 0x7fffu + ((u >> 16) & 1u)) >> 16;
    return (unsigned short)r;
}

// ---------------- projection: h = x @ Wp + bp  ([N,38]@[38,256]) -------------
#define NPB 4
__global__ __launch_bounds__(256) void proj_kernel(
    const float* __restrict__ x, const float* __restrict__ Wp,
    const float* __restrict__ bp, float* __restrict__ h) {
    __shared__ float xs[NPB][IN_DIM];
    int c = threadIdx.x;
    int n0 = blockIdx.x * NPB;
    for (int i = threadIdx.x; i < NPB * IN_DIM; i += 256) {
        int j = i / IN_DIM, k = i % IN_DIM;
        int n = n0 + j;
        xs[j][k] = (n < N_NODES) ? x[(size_t)n * IN_DIM + k] : 0.0f;
    }
    __syncthreads();
    float b = bp[c];
    float acc[NPB];
#pragma unroll
    for (int j = 0; j < NPB; j++) acc[j] = b;
    for (int k = 0; k < IN_DIM; k++) {
        float w = Wp[k * HID + c];
#pragma unroll
        for (int j = 0; j < NPB; j++) acc[j] += xs[j][k] * w;
    }
#pragma unroll
    for (int j = 0; j < NPB; j++) {
        int n = n0 + j;
        if (n < N_NODES) h[(size_t)n * HID + c] = acc[j];
    }
}

// ---------------- CSR build --------------------------------------------------
__global__ __launch_bounds__(256) void hist_kernel(const int* __restrict__ ei,
                                                   int* __restrict__ deg) {
    int e = blockIdx.x * 256 + threadIdx.x;
    if (e < N_EDGES) atomicAdd(&deg[ei[N_EDGES + e]], 1);
}

__global__ __launch_bounds__(256) void scan1_kernel(const int* __restrict__ deg,
                                                    int* __restrict__ offs,
                                                    int* __restrict__ blocksums) {
    __shared__ int s[SCAN_CHUNK];
    int base = blockIdx.x * SCAN_CHUNK;
    int t = threadIdx.x;
    int i0 = t, i1 = t + 256;
    int g0 = base + i0, g1 = base + i1;
    int o0 = (g0 < N_NODES) ? deg[g0] : 0;
    int o1 = (g1 < N_NODES) ? deg[g1] : 0;
    s[i0] = o0;
    s[i1] = o1;
    __syncthreads();
    for (int off = 1; off < SCAN_CHUNK; off <<= 1) {
        int v0 = (i0 >= off) ? s[i0 - off] : 0;
        int v1 = (i1 >= off) ? s[i1 - off] : 0;
        __syncthreads();
        s[i0] += v0;
        s[i1] += v1;
        __syncthreads();
    }
    if (g0 < N_NODES) offs[g0] = s[i0] - o0;
    if (g1 < N_NODES) offs[g1] = s[i1] - o1;
    if (t == 0) blocksums[blockIdx.x] = s[SCAN_CHUNK - 1];
}

__global__ __launch_bounds__(256) void scan2_kernel(int* __restrict__ blocksums) {
    __shared__ int s[256];
    int t = threadIdx.x;
    int o = (t < N_CHUNKS) ? blocksums[t] : 0;
    s[t] = o;
    __syncthreads();
    for (int off = 1; off < 256; off <<= 1) {
        int v = (t >= off) ? s[t - off] : 0;
        __syncthreads();
        s[t] += v;
        __syncthreads();
    }
    if (t < N_CHUNKS) blocksums[t] = s[t] - o;
}

__global__ __launch_bounds__(256) void scan3_kernel(int* __restrict__ offs,
                                                    const int* __restrict__ blocksums,
                                                    int* __restrict__ cursor) {
    int g = blockIdx.x * 256 + threadIdx.x;
    if (g < N_NODES) {
        int v = offs[g] + blocksums[g / SCAN_CHUNK];
        offs[g] = v;
        cursor[g] = v;
    }
    if (g == 0) offs[N_NODES] = N_EDGES;
}

__global__ __launch_bounds__(256) void fill_kernel(const int* __restrict__ ei,
                                                   int* __restrict__ cursor,
                                                   int* __restrict__ csr_src) {
    int e = blockIdx.x * 256 + threadIdx.x;
    if (e < N_EDGES) {
        int src = ei[e];
        int dst = ei[N_EDGES + e];
        int pos = atomicAdd(&cursor[dst], 1);
        csr_src[pos] = src;
    }
}

// ---------------- gather: z[i] = (1+eps)*h[i] + sum_{j->i} h[j] --------------
__global__ __launch_bounds__(256) void gather_kernel(
    const int* __restrict__ offs, const int* __restrict__ csr_src,
    const float* __restrict__ h, float* __restrict__ z,
    const float* __restrict__ eps, int layer) {
    int wave = threadIdx.x >> 6;
    int lane = threadIdx.x & 63;
    int node = blockIdx.x * 4 + wave;
    if (node >= N_NODES) return;
    float s = 1.0f + eps[layer];
    int beg = offs[node], end = offs[node + 1];
    float4 acc = *(const float4*)&h[(size_t)node * HID + lane * 4];
    acc.x *= s; acc.y *= s; acc.z *= s; acc.w *= s;
    for (int e = beg; e < end; e++) {
        int src = csr_src[e];
        float4 v = *(const float4*)&h[(size_t)src * HID + lane * 4];
        acc.x += v.x; acc.y += v.y; acc.z += v.z; acc.w += v.w;
    }
    *(float4*)&z[(size_t)node * HID + lane * 4] = acc;
}

// ---------------- weight packing: fragment-order bf16 hi/lo ------------------
// Wpk8[w*16384 + ((p*8+kt)*16+nt)*64 + lane] : short8 of
//   W[kt*32 + (lane>>4)*8 + e][nt*16 + (lane&15)]   (p=0 hi, p=1 lo)
__global__ __launch_bounds__(256) void packW_kernel(const float* __restrict__ W1s,
                                                    const float* __restrict__ W2s,
                                                    short8* __restrict__ Wpk8) {
    int id = blockIdx.x * 256 + threadIdx.x;  // < 81920
    int lane = id & 63;
    int fid = (id >> 6) & 127;  // kt*16+nt? -> kt = fid>>4, nt = fid&15
    int w = id >> 13;           // 0..9
    int kt = fid >> 4, nt = fid & 15;
    const float* Wsrc = (w < 5) ? W1s + (size_t)w * HID * HID
                                : W2s + (size_t)(w - 5) * HID * HID;
    int k0 = kt * 32 + ((lane >> 4) << 3);
    int n = nt * 16 + (lane & 15);
    short8 hi, lo;
#pragma unroll
    for (int e = 0; e < 8; e++) {
        float v = Wsrc[(size_t)(k0 + e) * HID + n];
        unsigned short hb = bf16_rne(v);
        float hf = __uint_as_float((unsigned int)hb << 16);
        unsigned short lb = bf16_rne(v - hf);
        hi[e] = (short)hb;
        lo[e] = (short)lb;
    }
    size_t base = (size_t)w * 16384;
    Wpk8[base + (size_t)((0 * 8 + kt) * 16 + nt) * 64 + lane] = hi;
    Wpk8[base + (size_t)((1 * 8 + kt) * 16 + nt) * 64 + lane] = lo;
}

// ---------------- split-bf16 MFMA GEMM: C = [relu](A @ W + bias) -------------
// A [M,256] fp32; W packed (above); BM=128 BN=128 BK=64; 256 thr = 4 waves,
// each wave a 64x64 quadrant (16 MFMA tiles, 3 passes hh/hl/lh).
__global__ __launch_bounds__(256, 2) void gemm_mfma_kernel(
    const float* __restrict__ A, const short8* __restrict__ Wm,
    const float* __restrict__ bias, float* __restrict__ C,
    int M, int doRelu) {
    __shared__ short8 As8[32 * 64];  // [p*16 + (ktl*8+mt)][lane]
    __shared__ short8 Bs8[32 * 64];  // [((p*2+ktl)*8+ntl)][lane]
    int t = threadIdx.x;
    int lane = t & 63;
    int w = t >> 6;
    int wm = w >> 1, wn = w & 1;
    int m0 = blockIdx.x * 128;
    int n0 = blockIdx.y * 128;
    int y = blockIdx.y;

    floatx4 acc[4][4];
#pragma unroll
    for (int i = 0; i < 4; i++)
#pragma unroll
        for (int j = 0; j < 4; j++) acc[i][j] = (floatx4)0.0f;

    for (int ki = 0; ki < 4; ki++) {
        // ---- stage A (fp32 -> bf16 hi/lo, fragment order) ----
#pragma unroll
        for (int q = 0; q < 4; q++) {
            int fa = t + q * 256;
            int la = fa & 63;
            int tile = fa >> 6;       // ktl*8 + mt
            int mt = tile & 7, ktl = tile >> 3;
            int m = m0 + mt * 16 + (la & 15);
            int kg = ki * 64 + ktl * 32 + ((la >> 4) << 3);
            float av[8];
            if (m < M) {
                float4 u0 = *(const float4*)&A[(size_t)m * HID + kg];
                float4 u1 = *(const float4*)&A[(size_t)m * HID + kg + 4];
                av[0] = u0.x; av[1] = u0.y; av[2] = u0.z; av[3] = u0.w;
                av[4] = u1.x; av[5] = u1.y; av[6] = u1.z; av[7] = u1.w;
            } else {
#pragma unroll
                for (int e = 0; e < 8; e++) av[e] = 0.0f;
            }
            short8 hi, lo;
#pragma unroll
            for (int e = 0; e < 8; e++) {
                unsigned short hb = bf16_rne(av[e]);
                float hf = __uint_as_float((unsigned int)hb << 16);
                unsigned short lb = bf16_rne(av[e] - hf);
                hi[e] = (short)hb;
                lo[e] = (short)lb;
            }
            As8[(0 * 16 + tile) * 64 + la] = hi;
            As8[(1 * 16 + tile) * 64 + la] = lo;
        }
        // ---- stage B (straight copy of packed fragments) ----
#pragma unroll
        for (int q = 0; q < 8; q++) {
            int fb = t + q * 256;
            int lb = fb & 63;
            int rest = fb >> 6;  // 0..31
            int ntl = rest & 7;
            int ktl = (rest >> 3) & 1;
            int p = rest >> 4;
            Bs8[(size_t)((p * 2 + ktl) * 8 + ntl) * 64 + lb] =
                Wm[(size_t)((p * 8 + (ki * 2 + ktl)) * 16 + (y * 8 + ntl)) * 64 + lb];
        }
        __syncthreads();
        // ---- compute ----
#pragma unroll
        for (int ktl = 0; ktl < 2; ktl++) {
            short8 ah[4], al[4], bh[4], bl[4];
#pragma unroll
            for (int i = 0; i < 4; i++) {
                ah[i] = As8[(0 * 16 + ktl * 8 + wm * 4 + i) * 64 + lane];
                al[i] = As8[(1 * 16 + ktl * 8 + wm * 4 + i) * 64 + lane];
            }
#pragma unroll
            for (int j = 0; j < 4; j++) {
                bh[j] = Bs8[((0 * 2 + ktl) * 8 + wn * 4 + j) * 64 + lane];
                bl[j] = Bs8[((1 * 2 + ktl) * 8 + wn * 4 + j) * 64 + lane];
            }
#pragma unroll
            for (int i = 0; i < 4; i++)
#pragma unroll
                for (int j = 0; j < 4; j++) {
                    acc[i][j] = __builtin_amdgcn_mfma_f32_16x16x32_bf16(
                        ah[i], bh[j], acc[i][j], 0, 0, 0);
                    acc[i][j] = __builtin_amdgcn_mfma_f32_16x16x32_bf16(
                        ah[i], bl[j], acc[i][j], 0, 0, 0);
                    acc[i][j] = __builtin_amdgcn_mfma_f32_16x16x32_bf16(
                        al[i], bh[j], acc[i][j], 0, 0, 0);
                }
        }
        __syncthreads();
    }

    // ---- epilogue: C = [relu](acc + bias) ----
    int col = lane & 15;
    int rbase = (lane >> 4) * 4;
#pragma unroll
    for (int j = 0; j < 4; j++) {
        int n = n0 + (wn * 4 + j) * 16 + col;
        float bv = bias[n];
#pragma unroll
        for (int i = 0; i < 4; i++) {
            int mbase = m0 + (wm * 4 + i) * 16 + rbase;
#pragma unroll
            for (int r = 0; r < 4; r++) {
                int m = mbase + r;
                if (m < M) {
                    float v = acc[i][j][r] + bv;
                    C[(size_t)m * HID + n] = doRelu ? fmaxf(v, 0.0f) : v;
                }
            }
        }
    }
}

// ---------------- BN stats: column sums / sumsq ------------------------------
__global__ __launch_bounds__(256) void stats_kernel(
    const float* __restrict__ z, float* __restrict__ sums,
    float* __restrict__ sumsq) {
    int c = threadIdx.x;
    float s = 0.f, sq = 0.f;
    for (int r = blockIdx.x; r < N_NODES; r += gridDim.x) {
        float v = z[(size_t)r * HID + c];
        s += v;
        sq += v * v;
    }
    atomicAdd(&sums[c], s);
    atomicAdd(&sumsq[c], sq);
}

__global__ void bnparams_kernel(const float* __restrict__ sums,
                                const float* __restrict__ sumsq,
                                const float* __restrict__ gammas,
                                const float* __restrict__ betas, int layer,
                                float* __restrict__ scale,
                                float* __restrict__ shift) {
    int c = threadIdx.x;
    float mu = sums[c] / (float)N_NODES;
    float var = sumsq[c] / (float)N_NODES - mu * mu;
    float rs = rsqrtf(var + BN_EPS);
    float g = gammas[layer * HID + c];
    scale[c] = rs * g;
    shift[c] = betas[layer * HID + c] - mu * rs * g;
}

// ---------------- h = relu(z * scale + shift) --------------------------------
__global__ __launch_bounds__(256) void bnrelu_kernel(
    const float* __restrict__ z, const float* __restrict__ scale,
    const float* __restrict__ shift, float* __restrict__ h) {
    int i = blockIdx.x * blockDim.x + threadIdx.x;
    const int total = N_NODES * HID / 4;
    if (i >= total) return;
    int c4 = i & 63;
    float4 v = ((const float4*)z)[i];
    float4 sc = ((const float4*)scale)[c4];
    float4 sh = ((const float4*)shift)[c4];
    v.x = fmaxf(v.x * sc.x + sh.x, 0.f);
    v.y = fmaxf(v.y * sc.y + sh.y, 0.f);
    v.z = fmaxf(v.z * sc.z + sh.z, 0.f);
    v.w = fmaxf(v.w * sc.w + sh.w, 0.f);
    ((float4*)h)[i] = v;
}

// ---------------- pooling (batch sorted -> segmented reduction) --------------
__global__ __launch_bounds__(256) void bounds_kernel(const int* __restrict__ batch,
                                                     int* __restrict__ start) {
    int g = blockIdx.x * 256 + threadIdx.x;
    if (g > N_GRAPHS) return;
    int lo = 0, hi = N_NODES;
    while (lo < hi) {
        int mid = (lo + hi) >> 1;
        if (batch[mid] < g) lo = mid + 1;
        else hi = mid;
    }
    start[g] = lo;
}

__global__ __launch_bounds__(256) void segpool_kernel(
    const float* __restrict__ h, const int* __restrict__ start,
    float* __restrict__ pooled) {
    int g = blockIdx.x;
    int c = threadIdx.x;
    int beg = start[g], end = start[g + 1];
    float s = 0.f;
    for (int n = beg; n < end; n++) s += h[(size_t)n * HID + c];
    float inv = 1.0f / fmaxf((float)(end - beg), 1.0f);
    pooled[(size_t)g * HID + c] = s * inv;
}

// ---------------- readout ----------------------------------------------------
__global__ __launch_bounds__(256) void readout_kernel(
    const float* __restrict__ pooled, const float* __restrict__ Wr1,
    const float* __restrict__ br1, const float* __restrict__ Wr2,
    const float* __restrict__ br2, float* __restrict__ out) {
    __shared__ float p[HID];
    __shared__ float red[4];
    int g = blockIdx.x;
    int c = threadIdx.x;
    p[c] = pooled[(size_t)g * HID + c];
    __syncthreads();
    float acc = br1[c];
    for (int k = 0; k < HID; k++) acc += p[k] * Wr1[k * HID + c];
    acc = fmaxf(acc, 0.f);
    float v = acc * Wr2[c];
#pragma unroll
    for (int off = 32; off > 0; off >>= 1) v += __shfl_down(v, off, 64);
    if ((c & 63) == 0) red[c >> 6] = v;
    __syncthreads();
    if (c == 0) out[g] = red[0] + red[1] + red[2] + red[3] + br2[0];
}

extern "C" void kernel_launch(void* const* d_in, const int* in_sizes, int n_in,
                              void* d_out, int out_size, void* d_ws, size_t ws_size,
                              hipStream_t stream) {
    const float* x      = (const float*)d_in[0];
    const int*   ei     = (const int*)d_in[1];
    const int*   batch  = (const int*)d_in[2];
    const float* Wp     = (const float*)d_in[3];
    const float* bp     = (const float*)d_in[4];
    const float* eps    = (const float*)d_in[5];
    const float* W1s    = (const float*)d_in[6];
    const float* b1s    = (const float*)d_in[7];
    const float* W2s    = (const float*)d_in[8];
    const float* b2s    = (const float*)d_in[9];
    const float* gammas = (const float*)d_in[10];
    const float* betas  = (const float*)d_in[11];
    const float* Wr1    = (const float*)d_in[12];
    const float* br1    = (const float*)d_in[13];
    const float* Wr2    = (const float*)d_in[14];
    const float* br2    = (const float*)d_in[15];
    float* out = (float*)d_out;

    const size_t NH = (size_t)N_NODES * HID;
    float* h      = (float*)d_ws;
    float* z      = h + NH;
    short8* Wpk8  = (short8*)(z + NH);            // 10*16384 short8 = 2.62 MB
    float* sums   = (float*)(Wpk8 + 10 * 16384);
    float* sumsq  = sums + HID;
    float* scale  = sumsq + HID;
    float* shift  = scale + HID;
    float* pooled = shift + HID;
    int* start     = (int*)(pooled + (size_t)N_GRAPHS * HID);  // N_GRAPHS+1
    int* deg       = start + N_GRAPHS + 1;
    int* offs      = deg + N_NODES;        // N_NODES+1
    int* cursor    = offs + N_NODES + 1;
    int* csr_src   = cursor + N_NODES;
    int* blocksums = csr_src + N_EDGES;    // N_CHUNKS

    const int ELT4_BLOCKS = (N_NODES * HID / 4 + 255) / 256;
    const dim3 GEMM_GRID((N_NODES + 127) / 128, 2);

    // ---- CSR build + weight packing (once per launch) ----
    hipMemsetAsync(deg, 0, N_NODES * sizeof(int), stream);
    hist_kernel<<<(N_EDGES + 255) / 256, 256, 0, stream>>>(ei, deg);
    scan1_kernel<<<N_CHUNKS, 256, 0, stream>>>(deg, offs, blocksums);
    scan2_kernel<<<1, 256, 0, stream>>>(blocksums);
    scan3_kernel<<<(N_NODES + 255) / 256, 256, 0, stream>>>(offs, blocksums,
                                                            cursor);
    fill_kernel<<<(N_EDGES + 255) / 256, 256, 0, stream>>>(ei, cursor, csr_src);
    packW_kernel<<<320, 256, 0, stream>>>(W1s, W2s, Wpk8);
    bounds_kernel<<<(N_GRAPHS + 1 + 255) / 256, 256, 0, stream>>>(batch, start);

    // h = x @ Wp + bp
    proj_kernel<<<(N_NODES + NPB - 1) / NPB, 256, 0, stream>>>(x, Wp, bp, h);

    for (int l = 0; l < LAYERS; l++) {
        gather_kernel<<<(N_NODES + 3) / 4, 256, 0, stream>>>(offs, csr_src, h, z,
                                                             eps, l);
        // h = relu(z @ W1 + b1)
        gemm_mfma_kernel<<<GEMM_GRID, 256, 0, stream>>>(
            z, Wpk8 + (size_t)l * 16384, b1s + l * HID, h, N_NODES, 1);
        // z = h @ W2 + b2
        gemm_mfma_kernel<<<GEMM_GRID, 256, 0, stream>>>(
            h, Wpk8 + (size_t)(5 + l) * 16384, b2s + l * HID, z, N_NODES, 0);
        hipMemsetAsync(sums, 0, 2 * HID * sizeof(float), stream);
        stats_kernel<<<2000, 256, 0, stream>>>(z, sums, sumsq);
        bnparams_kernel<<<1, HID, 0, stream>>>(sums, sumsq, gammas, betas, l,
                                               scale, shift);
        bnrelu_kernel<<<ELT4_BLOCKS, 256, 0, stream>>>(z, scale, shift, h);
    }

    segpool_kernel<<<N_GRAPHS, 256, 0, stream>>>(h, start, pooled);
    readout_kernel<<<N_GRAPHS, 256, 0, stream>>>(pooled, Wr1, br1, Wr2, br2, out);
}

// Round 5
// 1731.394 us; speedup vs baseline: 4.5284x; 1.2016x over previous
//
#include <hip/hip_runtime.h>

#define N_NODES 100000
#define N_EDGES 300000
#define N_GRAPHS 2048
#define IN_DIM 38
#define HID 256
#define LAYERS 5
#define BN_EPS 1e-5f

#define SCAN_CHUNK 512
#define N_CHUNKS ((N_NODES + SCAN_CHUNK - 1) / SCAN_CHUNK)  // 196

typedef __attribute__((ext_vector_type(8))) short short8;   // 8 bf16 = 4 VGPR
typedef __attribute__((ext_vector_type(4))) float floatx4;  // MFMA acc

__device__ inline unsigned short bf16_rne(float f) {
    unsigned int u = __float_as_uint(f);
    unsigned int r = (u + 0x7fffu + ((u >> 16) & 1u)) >> 16;
    return (unsigned short)r;
}

// ---------------- projection: h = x @ Wp + bp  ([N,38]@[38,256]) -------------
// thread t owns channel t; Wp column in registers; x staged per 64-node chunk.
#define PROJ_CH 64
__global__ __launch_bounds__(256) void proj_kernel(
    const float* __restrict__ x, const float* __restrict__ Wp,
    const float* __restrict__ bp, float* __restrict__ h) {
    __shared__ float xs[PROJ_CH * IN_DIM];
    int t = threadIdx.x;
    float w[IN_DIM];
#pragma unroll
    for (int k = 0; k < IN_DIM; k++) w[k] = Wp[k * HID + t];
    float b = bp[t];
    int n0 = blockIdx.x * PROJ_CH;
    int count = min(PROJ_CH, N_NODES - n0);
    int total = count * IN_DIM;
    const float* xbase = x + (size_t)n0 * IN_DIM;
    for (int i = t; i < total; i += 256) xs[i] = xbase[i];
    __syncthreads();
    for (int n = 0; n < count; n++) {
        float acc = b;
        const float* xr = &xs[n * IN_DIM];
#pragma unroll
        for (int k = 0; k < IN_DIM; k++) acc = fmaf(xr[k], w[k], acc);
        h[(size_t)(n0 + n) * HID + t] = acc;
    }
}

// ---------------- CSR build --------------------------------------------------
__global__ __launch_bounds__(256) void hist_kernel(const int* __restrict__ ei,
                                                   int* __restrict__ deg) {
    int e = blockIdx.x * 256 + threadIdx.x;
    if (e < N_EDGES) atomicAdd(&deg[ei[N_EDGES + e]], 1);
}

__global__ __launch_bounds__(256) void scan1_kernel(const int* __restrict__ deg,
                                                    int* __restrict__ offs,
                                                    int* __restrict__ blocksums) {
    __shared__ int s[SCAN_CHUNK];
    int base = blockIdx.x * SCAN_CHUNK;
    int t = threadIdx.x;
    int i0 = t, i1 = t + 256;
    int g0 = base + i0, g1 = base + i1;
    int o0 = (g0 < N_NODES) ? deg[g0] : 0;
    int o1 = (g1 < N_NODES) ? deg[g1] : 0;
    s[i0] = o0;
    s[i1] = o1;
    __syncthreads();
    for (int off = 1; off < SCAN_CHUNK; off <<= 1) {
        int v0 = (i0 >= off) ? s[i0 - off] : 0;
        int v1 = (i1 >= off) ? s[i1 - off] : 0;
        __syncthreads();
        s[i0] += v0;
        s[i1] += v1;
        __syncthreads();
    }
    if (g0 < N_NODES) offs[g0] = s[i0] - o0;
    if (g1 < N_NODES) offs[g1] = s[i1] - o1;
    if (t == 0) blocksums[blockIdx.x] = s[SCAN_CHUNK - 1];
}

__global__ __launch_bounds__(256) void scan2_kernel(int* __restrict__ blocksums) {
    __shared__ int s[256];
    int t = threadIdx.x;
    int o = (t < N_CHUNKS) ? blocksums[t] : 0;
    s[t] = o;
    __syncthreads();
    for (int off = 1; off < 256; off <<= 1) {
        int v = (t >= off) ? s[t - off] : 0;
        __syncthreads();
        s[t] += v;
        __syncthreads();
    }
    if (t < N_CHUNKS) blocksums[t] = s[t] - o;
}

__global__ __launch_bounds__(256) void scan3_kernel(int* __restrict__ offs,
                                                    const int* __restrict__ blocksums,
                                                    int* __restrict__ cursor) {
    int g = blockIdx.x * 256 + threadIdx.x;
    if (g < N_NODES) {
        int v = offs[g] + blocksums[g / SCAN_CHUNK];
        offs[g] = v;
        cursor[g] = v;
    }
    if (g == 0) offs[N_NODES] = N_EDGES;
}

__global__ __launch_bounds__(256) void fill_kernel(const int* __restrict__ ei,
                                                   int* __restrict__ cursor,
                                                   int* __restrict__ csr_src) {
    int e = blockIdx.x * 256 + threadIdx.x;
    if (e < N_EDGES) {
        int src = ei[e];
        int dst = ei[N_EDGES + e];
        int pos = atomicAdd(&cursor[dst], 1);
        csr_src[pos] = src;
    }
}

// ---- gather with fused BN+relu on the INPUT (z of prev layer) ----
// out[i] = (1+eps)*f(z[i]) + sum_{j->i} f(z[j]);  f = useBN ? relu(v*sc+sh) : v
__global__ __launch_bounds__(256) void gather_kernel(
    const int* __restrict__ offs, const int* __restrict__ csr_src,
    const float* __restrict__ zin, float* __restrict__ zout,
    const float* __restrict__ eps, int layer,
    const float* __restrict__ scale, const float* __restrict__ shift,
    int useBN) {
    int wave = threadIdx.x >> 6;
    int lane = threadIdx.x & 63;
    int node = blockIdx.x * 4 + wave;
    if (node >= N_NODES) return;
    float s = 1.0f + eps[layer];
    float4 sc = make_float4(1.f, 1.f, 1.f, 1.f);
    float4 sh = make_float4(0.f, 0.f, 0.f, 0.f);
    if (useBN) {
        sc = *(const float4*)&scale[lane * 4];
        sh = *(const float4*)&shift[lane * 4];
    }
    int beg = offs[node], end = offs[node + 1];
    float4 acc = *(const float4*)&zin[(size_t)node * HID + lane * 4];
    if (useBN) {
        acc.x = fmaxf(acc.x * sc.x + sh.x, 0.f);
        acc.y = fmaxf(acc.y * sc.y + sh.y, 0.f);
        acc.z = fmaxf(acc.z * sc.z + sh.z, 0.f);
        acc.w = fmaxf(acc.w * sc.w + sh.w, 0.f);
    }
    acc.x *= s; acc.y *= s; acc.z *= s; acc.w *= s;
    for (int e = beg; e < end; e++) {
        int src = csr_src[e];
        float4 v = *(const float4*)&zin[(size_t)src * HID + lane * 4];
        if (useBN) {
            v.x = fmaxf(v.x * sc.x + sh.x, 0.f);
            v.y = fmaxf(v.y * sc.y + sh.y, 0.f);
            v.z = fmaxf(v.z * sc.z + sh.z, 0.f);
            v.w = fmaxf(v.w * sc.w + sh.w, 0.f);
        }
        acc.x += v.x; acc.y += v.y; acc.z += v.z; acc.w += v.w;
    }
    *(float4*)&zout[(size_t)node * HID + lane * 4] = acc;
}

// ---------------- weight packing: fragment-order bf16 hi/lo ------------------
__global__ __launch_bounds__(256) void packW_kernel(const float* __restrict__ W1s,
                                                    const float* __restrict__ W2s,
                                                    short8* __restrict__ Wpk8) {
    int id = blockIdx.x * 256 + threadIdx.x;  // < 81920
    int lane = id & 63;
    int fid = (id >> 6) & 127;
    int w = id >> 13;  // 0..9
    int kt = fid >> 4, nt = fid & 15;
    const float* Wsrc = (w < 5) ? W1s + (size_t)w * HID * HID
                                : W2s + (size_t)(w - 5) * HID * HID;
    int k0 = kt * 32 + ((lane >> 4) << 3);
    int n = nt * 16 + (lane & 15);
    short8 hi, lo;
#pragma unroll
    for (int e = 0; e < 8; e++) {
        float v = Wsrc[(size_t)(k0 + e) * HID + n];
        unsigned short hb = bf16_rne(v);
        float hf = __uint_as_float((unsigned int)hb << 16);
        unsigned short lb = bf16_rne(v - hf);
        hi[e] = (short)hb;
        lo[e] = (short)lb;
    }
    size_t base = (size_t)w * 16384;
    Wpk8[base + (size_t)((0 * 8 + kt) * 16 + nt) * 64 + lane] = hi;
    Wpk8[base + (size_t)((1 * 8 + kt) * 16 + nt) * 64 + lane] = lo;
}

// ---------------- split-bf16 MFMA GEMM, optional fused BN stats --------------
__global__ __launch_bounds__(256, 2) void gemm_mfma_kernel(
    const float* __restrict__ A, const short8* __restrict__ Wm,
    const float* __restrict__ bias, float* __restrict__ C,
    int M, int doRelu, int doStats,
    float* __restrict__ sums, float* __restrict__ sumsq) {
    __shared__ short8 As8[32 * 64];
    __shared__ short8 Bs8[32 * 64];
    int t = threadIdx.x;
    int lane = t & 63;
    int w = t >> 6;
    int wm = w >> 1, wn = w & 1;
    int m0 = blockIdx.x * 128;
    int n0 = blockIdx.y * 128;
    int y = blockIdx.y;

    floatx4 acc[4][4];
#pragma unroll
    for (int i = 0; i < 4; i++)
#pragma unroll
        for (int j = 0; j < 4; j++) acc[i][j] = (floatx4)0.0f;

    for (int ki = 0; ki < 4; ki++) {
        // ---- stage A (fp32 -> bf16 hi + truncated lo, fragment order) ----
#pragma unroll
        for (int q = 0; q < 4; q++) {
            int fa = t + q * 256;
            int la = fa & 63;
            int tile = fa >> 6;
            int mt = tile & 7, ktl = tile >> 3;
            int m = m0 + mt * 16 + (la & 15);
            int kg = ki * 64 + ktl * 32 + ((la >> 4) << 3);
            float av[8];
            if (m < M) {
                float4 u0 = *(const float4*)&A[(size_t)m * HID + kg];
                float4 u1 = *(const float4*)&A[(size_t)m * HID + kg + 4];
                av[0] = u0.x; av[1] = u0.y; av[2] = u0.z; av[3] = u0.w;
                av[4] = u1.x; av[5] = u1.y; av[6] = u1.z; av[7] = u1.w;
            } else {
#pragma unroll
                for (int e = 0; e < 8; e++) av[e] = 0.0f;
            }
            short8 hi, lo;
#pragma unroll
            for (int e = 0; e < 8; e++) {
                unsigned short hb = bf16_rne(av[e]);
                float hf = __uint_as_float((unsigned int)hb << 16);
                lo[e] = (short)(unsigned short)(__float_as_uint(av[e] - hf) >> 16);
                hi[e] = (short)hb;
            }
            As8[(0 * 16 + tile) * 64 + la] = hi;
            As8[(1 * 16 + tile) * 64 + la] = lo;
        }
        // ---- stage B ----
#pragma unroll
        for (int q = 0; q < 8; q++) {
            int fb = t + q * 256;
            int lb = fb & 63;
            int rest = fb >> 6;
            int ntl = rest & 7;
            int ktl = (rest >> 3) & 1;
            int p = rest >> 4;
            Bs8[(size_t)((p * 2 + ktl) * 8 + ntl) * 64 + lb] =
                Wm[(size_t)((p * 8 + (ki * 2 + ktl)) * 16 + (y * 8 + ntl)) * 64 + lb];
        }
        __syncthreads();
        // ---- compute ----
#pragma unroll
        for (int ktl = 0; ktl < 2; ktl++) {
            short8 ah[4], al[4], bh[4], bl[4];
#pragma unroll
            for (int i = 0; i < 4; i++) {
                ah[i] = As8[(0 * 16 + ktl * 8 + wm * 4 + i) * 64 + lane];
                al[i] = As8[(1 * 16 + ktl * 8 + wm * 4 + i) * 64 + lane];
            }
#pragma unroll
            for (int j = 0; j < 4; j++) {
                bh[j] = Bs8[((0 * 2 + ktl) * 8 + wn * 4 + j) * 64 + lane];
                bl[j] = Bs8[((1 * 2 + ktl) * 8 + wn * 4 + j) * 64 + lane];
            }
#pragma unroll
            for (int i = 0; i < 4; i++)
#pragma unroll
                for (int j = 0; j < 4; j++) {
                    acc[i][j] = __builtin_amdgcn_mfma_f32_16x16x32_bf16(
                        ah[i], bh[j], acc[i][j], 0, 0, 0);
                    acc[i][j] = __builtin_amdgcn_mfma_f32_16x16x32_bf16(
                        ah[i], bl[j], acc[i][j], 0, 0, 0);
                    acc[i][j] = __builtin_amdgcn_mfma_f32_16x16x32_bf16(
                        al[i], bh[j], acc[i][j], 0, 0, 0);
                }
        }
        __syncthreads();
    }

    // ---- epilogue: C = [relu](acc + bias), optional column stats ----
    int col = lane & 15;
    int rbase = (lane >> 4) * 4;
#pragma unroll
    for (int j = 0; j < 4; j++) {
        int n = n0 + (wn * 4 + j) * 16 + col;
        float bv = bias[n];
        float csum = 0.f, csq = 0.f;
#pragma unroll
        for (int i = 0; i < 4; i++) {
            int mbase = m0 + (wm * 4 + i) * 16 + rbase;
#pragma unroll
            for (int r = 0; r < 4; r++) {
                int m = mbase + r;
                if (m < M) {
                    float v = acc[i][j][r] + bv;
                    if (doRelu) v = fmaxf(v, 0.0f);
                    C[(size_t)m * HID + n] = v;
                    csum += v;
                    csq += v * v;
                }
            }
        }
        if (doStats) {
            csum += __shfl_xor(csum, 16);
            csum += __shfl_xor(csum, 32);
            csq += __shfl_xor(csq, 16);
            csq += __shfl_xor(csq, 32);
            if ((lane >> 4) == 0) {
                atomicAdd(&sums[n], csum);
                atomicAdd(&sumsq[n], csq);
            }
        }
    }
}

__global__ void bnparams_kernel(const float* __restrict__ sums,
                                const float* __restrict__ sumsq,
                                const float* __restrict__ gammas,
                                const float* __restrict__ betas, int layer,
                                float* __restrict__ scale,
                                float* __restrict__ shift) {
    int c = threadIdx.x;
    float mu = sums[c] / (float)N_NODES;
    float var = sumsq[c] / (float)N_NODES - mu * mu;
    float rs = rsqrtf(var + BN_EPS);
    float g = gammas[layer * HID + c];
    scale[c] = rs * g;
    shift[c] = betas[layer * HID + c] - mu * rs * g;
}

// ---------------- pooling (batch sorted), fused final BN+relu ----------------
__global__ __launch_bounds__(256) void bounds_kernel(const int* __restrict__ batch,
                                                     int* __restrict__ start) {
    int g = blockIdx.x * 256 + threadIdx.x;
    if (g > N_GRAPHS) return;
    int lo = 0, hi = N_NODES;
    while (lo < hi) {
        int mid = (lo + hi) >> 1;
        if (batch[mid] < g) lo = mid + 1;
        else hi = mid;
    }
    start[g] = lo;
}

__global__ __launch_bounds__(256) void segpool_kernel(
    const float* __restrict__ z, const int* __restrict__ start,
    const float* __restrict__ scale, const float* __restrict__ shift,
    float* __restrict__ pooled) {
    int g = blockIdx.x;
    int c = threadIdx.x;
    float sc = scale[c], sh = shift[c];
    int beg = start[g], end = start[g + 1];
    float s = 0.f;
    for (int n = beg; n < end; n++)
        s += fmaxf(z[(size_t)n * HID + c] * sc + sh, 0.f);
    float inv = 1.0f / fmaxf((float)(end - beg), 1.0f);
    pooled[(size_t)g * HID + c] = s * inv;
}

// ---------------- readout ----------------------------------------------------
__global__ __launch_bounds__(256) void readout_kernel(
    const float* __restrict__ pooled, const float* __restrict__ Wr1,
    const float* __restrict__ br1, const float* __restrict__ Wr2,
    const float* __restrict__ br2, float* __restrict__ out) {
    __shared__ float p[HID];
    __shared__ float red[4];
    int g = blockIdx.x;
    int c = threadIdx.x;
    p[c] = pooled[(size_t)g * HID + c];
    __syncthreads();
    float acc = br1[c];
    for (int k = 0; k < HID; k++) acc += p[k] * Wr1[k * HID + c];
    acc = fmaxf(acc, 0.f);
    float v = acc * Wr2[c];
#pragma unroll
    for (int off = 32; off > 0; off >>= 1) v += __shfl_down(v, off, 64);
    if ((c & 63) == 0) red[c >> 6] = v;
    __syncthreads();
    if (c == 0) out[g] = red[0] + red[1] + red[2] + red[3] + br2[0];
}

extern "C" void kernel_launch(void* const* d_in, const int* in_sizes, int n_in,
                              void* d_out, int out_size, void* d_ws, size_t ws_size,
                              hipStream_t stream) {
    const float* x      = (const float*)d_in[0];
    const int*   ei     = (const int*)d_in[1];
    const int*   batch  = (const int*)d_in[2];
    const float* Wp     = (const float*)d_in[3];
    const float* bp     = (const float*)d_in[4];
    const float* eps    = (const float*)d_in[5];
    const float* W1s    = (const float*)d_in[6];
    const float* b1s    = (const float*)d_in[7];
    const float* W2s    = (const float*)d_in[8];
    const float* b2s    = (const float*)d_in[9];
    const float* gammas = (const float*)d_in[10];
    const float* betas  = (const float*)d_in[11];
    const float* Wr1    = (const float*)d_in[12];
    const float* br1    = (const float*)d_in[13];
    const float* Wr2    = (const float*)d_in[14];
    const float* br2    = (const float*)d_in[15];
    float* out = (float*)d_out;

    const size_t NH = (size_t)N_NODES * HID;
    float* bufA   = (float*)d_ws;
    float* bufB   = bufA + NH;
    short8* Wpk8  = (short8*)(bufB + NH);         // 10*16384 short8 = 2.62 MB
    float* sums   = (float*)(Wpk8 + 10 * 16384);
    float* sumsq  = sums + HID;
    float* scale  = sumsq + HID;
    float* shift  = scale + HID;
    float* pooled = shift + HID;
    int* start     = (int*)(pooled + (size_t)N_GRAPHS * HID);  // N_GRAPHS+1
    int* deg       = start + N_GRAPHS + 1;
    int* offs      = deg + N_NODES;        // N_NODES+1
    int* cursor    = offs + N_NODES + 1;
    int* csr_src   = cursor + N_NODES;
    int* blocksums = csr_src + N_EDGES;    // N_CHUNKS

    const dim3 GEMM_GRID((N_NODES + 127) / 128, 2);

    // ---- CSR build + weight packing (once per launch) ----
    hipMemsetAsync(deg, 0, N_NODES * sizeof(int), stream);
    hist_kernel<<<(N_EDGES + 255) / 256, 256, 0, stream>>>(ei, deg);
    scan1_kernel<<<N_CHUNKS, 256, 0, stream>>>(deg, offs, blocksums);
    scan2_kernel<<<1, 256, 0, stream>>>(blocksums);
    scan3_kernel<<<(N_NODES + 255) / 256, 256, 0, stream>>>(offs, blocksums,
                                                            cursor);
    fill_kernel<<<(N_EDGES + 255) / 256, 256, 0, stream>>>(ei, cursor, csr_src);
    packW_kernel<<<320, 256, 0, stream>>>(W1s, W2s, Wpk8);
    bounds_kernel<<<(N_GRAPHS + 1 + 255) / 256, 256, 0, stream>>>(batch, start);

    // h0 = x @ Wp + bp  -> bufA
    proj_kernel<<<(N_NODES + PROJ_CH - 1) / PROJ_CH, 256, 0, stream>>>(x, Wp, bp,
                                                                       bufA);

    float* A = bufA;  // holds prev-layer z (or h0), pre-BN
    float* B = bufB;
    for (int l = 0; l < LAYERS; l++) {
        hipMemsetAsync(sums, 0, 2 * HID * sizeof(float), stream);
        // B = (1+eps)*f(A) + sum f(A[src]);  f = BN(l-1)+relu for l>0
        gather_kernel<<<(N_NODES + 3) / 4, 256, 0, stream>>>(
            offs, csr_src, A, B, eps, l, scale, shift, l > 0 ? 1 : 0);
        // A = relu(B @ W1 + b1)
        gemm_mfma_kernel<<<GEMM_GRID, 256, 0, stream>>>(
            B, Wpk8 + (size_t)l * 16384, b1s + l * HID, A, N_NODES, 1, 0,
            sums, sumsq);
        // B = A @ W2 + b2  (+ fused column stats)
        gemm_mfma_kernel<<<GEMM_GRID, 256, 0, stream>>>(
            A, Wpk8 + (size_t)(5 + l) * 16384, b2s + l * HID, B, N_NODES, 0, 1,
            sums, sumsq);
        bnparams_kernel<<<1, HID, 0, stream>>>(sums, sumsq, gammas, betas, l,
                                               scale, shift);
        float* tmp = A; A = B; B = tmp;  // next layer's input = this z
    }

    // A holds z4 (pre-BN); segpool applies BN(4)+relu inline
    segpool_kernel<<<N_GRAPHS, 256, 0, stream>>>(A, start, scale, shift, pooled);
    readout_kernel<<<N_GRAPHS, 256, 0, stream>>>(pooled, Wr1, br1, Wr2, br2, out);
}

// Round 6
// 1460.519 us; speedup vs baseline: 5.3683x; 1.1855x over previous
//
#include <hip/hip_runtime.h>

#define N_NODES 100000
#define N_EDGES 300000
#define N_GRAPHS 2048
#define IN_DIM 38
#define HID 256
#define LAYERS 5
#define BN_EPS 1e-5f

#define SCAN_CHUNK 512
#define N_CHUNKS ((N_NODES + SCAN_CHUNK - 1) / SCAN_CHUNK)  // 196

// activation storage: split bf16 planes, row stride 512 ushorts:
//   buf[m*512 + c]       = hi bf16 bits of channel c
//   buf[m*512 + 256 + c] = lo bf16 bits (truncated residual)
#define ROW_PAD 128  // pad rows so unguarded global_load_lds A-staging stays in-bounds

typedef unsigned short u16;
typedef __attribute__((ext_vector_type(8))) short short8;       // 8 bf16 = 4 VGPR
typedef __attribute__((ext_vector_type(8))) unsigned short ushort8;
typedef __attribute__((ext_vector_type(4))) unsigned short ushortx4;
typedef __attribute__((ext_vector_type(4))) float floatx4;      // MFMA acc

__device__ __forceinline__ unsigned short bf16_rne(float f) {
    unsigned int u = __float_as_uint(f);
    unsigned int r = (u + 0x7fffu + ((u >> 16) & 1u)) >> 16;
    return (unsigned short)r;
}
__device__ __forceinline__ float uf(unsigned short b) {
    return __uint_as_float((unsigned int)b << 16);
}
__device__ __forceinline__ void split_bf16(float v, unsigned short& hi,
                                           unsigned short& lo) {
    hi = bf16_rne(v);
    float hf = __uint_as_float((unsigned int)hi << 16);
    lo = (unsigned short)(__float_as_uint(v - hf) >> 16);  // truncated residual
}
// async 16B global -> LDS (HW dest = wave-uniform base + lane*16)
__device__ __forceinline__ void load16_to_lds(const void* g, void* l) {
    __builtin_amdgcn_global_load_lds(
        (const __attribute__((address_space(1))) unsigned int*)g,
        (__attribute__((address_space(3))) unsigned int*)l, 16, 0, 0);
}

// ---------------- projection: h = x @ Wp + bp  ([N,38]@[38,256]) -------------
#define PROJ_CH 64
__global__ __launch_bounds__(256) void proj_kernel(
    const float* __restrict__ x, const float* __restrict__ Wp,
    const float* __restrict__ bp, u16* __restrict__ h) {
    __shared__ float xs[PROJ_CH * IN_DIM];
    int t = threadIdx.x;
    float w[IN_DIM];
#pragma unroll
    for (int k = 0; k < IN_DIM; k++) w[k] = Wp[k * HID + t];
    float b = bp[t];
    int n0 = blockIdx.x * PROJ_CH;
    int count = min(PROJ_CH, N_NODES - n0);
    int total = count * IN_DIM;
    const float* xbase = x + (size_t)n0 * IN_DIM;
    for (int i = t; i < total; i += 256) xs[i] = xbase[i];
    __syncthreads();
    for (int n = 0; n < count; n++) {
        float acc = b;
        const float* xr = &xs[n * IN_DIM];
#pragma unroll
        for (int k = 0; k < IN_DIM; k++) acc = fmaf(xr[k], w[k], acc);
        unsigned short hb, lb;
        split_bf16(acc, hb, lb);
        h[(size_t)(n0 + n) * 512 + t] = hb;
        h[(size_t)(n0 + n) * 512 + 256 + t] = lb;
    }
}

// ---------------- CSR build --------------------------------------------------
__global__ __launch_bounds__(256) void hist_kernel(const int* __restrict__ ei,
                                                   int* __restrict__ deg) {
    int e = blockIdx.x * 256 + threadIdx.x;
    if (e < N_EDGES) atomicAdd(&deg[ei[N_EDGES + e]], 1);
}

__global__ __launch_bounds__(256) void scan1_kernel(const int* __restrict__ deg,
                                                    int* __restrict__ offs,
                                                    int* __restrict__ blocksums) {
    __shared__ int s[SCAN_CHUNK];
    int base = blockIdx.x * SCAN_CHUNK;
    int t = threadIdx.x;
    int i0 = t, i1 = t + 256;
    int g0 = base + i0, g1 = base + i1;
    int o0 = (g0 < N_NODES) ? deg[g0] : 0;
    int o1 = (g1 < N_NODES) ? deg[g1] : 0;
    s[i0] = o0;
    s[i1] = o1;
    __syncthreads();
    for (int off = 1; off < SCAN_CHUNK; off <<= 1) {
        int v0 = (i0 >= off) ? s[i0 - off] : 0;
        int v1 = (i1 >= off) ? s[i1 - off] : 0;
        __syncthreads();
        s[i0] += v0;
        s[i1] += v1;
        __syncthreads();
    }
    if (g0 < N_NODES) offs[g0] = s[i0] - o0;
    if (g1 < N_NODES) offs[g1] = s[i1] - o1;
    if (t == 0) blocksums[blockIdx.x] = s[SCAN_CHUNK - 1];
}

__global__ __launch_bounds__(256) void scan2_kernel(int* __restrict__ blocksums) {
    __shared__ int s[256];
    int t = threadIdx.x;
    int o = (t < N_CHUNKS) ? blocksums[t] : 0;
    s[t] = o;
    __syncthreads();
    for (int off = 1; off < 256; off <<= 1) {
        int v = (t >= off) ? s[t - off] : 0;
        __syncthreads();
        s[t] += v;
        __syncthreads();
    }
    if (t < N_CHUNKS) blocksums[t] = s[t] - o;
}

__global__ __launch_bounds__(256) void scan3_kernel(int* __restrict__ offs,
                                                    const int* __restrict__ blocksums,
                                                    int* __restrict__ cursor) {
    int g = blockIdx.x * 256 + threadIdx.x;
    if (g < N_NODES) {
        int v = offs[g] + blocksums[g / SCAN_CHUNK];
        offs[g] = v;
        cursor[g] = v;
    }
    if (g == 0) offs[N_NODES] = N_EDGES;
}

__global__ __launch_bounds__(256) void fill_kernel(const int* __restrict__ ei,
                                                   int* __restrict__ cursor,
                                                   int* __restrict__ csr_src) {
    int e = blockIdx.x * 256 + threadIdx.x;
    if (e < N_EDGES) {
        int src = ei[e];
        int dst = ei[N_EDGES + e];
        int pos = atomicAdd(&cursor[dst], 1);
        csr_src[pos] = src;
    }
}

// ---- gather with fused BN+relu on the INPUT; split-bf16 in and out ----------
__global__ __launch_bounds__(256) void gather_kernel(
    const int* __restrict__ offs, const int* __restrict__ csr_src,
    const u16* __restrict__ zin, u16* __restrict__ zout,
    const float* __restrict__ eps, int layer,
    const float* __restrict__ scale, const float* __restrict__ shift,
    int useBN) {
    int wave = threadIdx.x >> 6;
    int lane = threadIdx.x & 63;
    int node = blockIdx.x * 4 + wave;
    if (node >= N_NODES) return;
    float s = 1.0f + eps[layer];
    int c0 = lane * 4;
    float4 sc = make_float4(1.f, 1.f, 1.f, 1.f);
    float4 sh = make_float4(0.f, 0.f, 0.f, 0.f);
    if (useBN) {
        sc = *(const float4*)&scale[c0];
        sh = *(const float4*)&shift[c0];
    }
    int beg = offs[node], end = offs[node + 1];
    float acc[4];
    {
        ushortx4 hi = *(const ushortx4*)&zin[(size_t)node * 512 + c0];
        ushortx4 lo = *(const ushortx4*)&zin[(size_t)node * 512 + 256 + c0];
        acc[0] = uf(hi[0]) + uf(lo[0]);
        acc[1] = uf(hi[1]) + uf(lo[1]);
        acc[2] = uf(hi[2]) + uf(lo[2]);
        acc[3] = uf(hi[3]) + uf(lo[3]);
    }
    if (useBN) {
        acc[0] = fmaxf(acc[0] * sc.x + sh.x, 0.f);
        acc[1] = fmaxf(acc[1] * sc.y + sh.y, 0.f);
        acc[2] = fmaxf(acc[2] * sc.z + sh.z, 0.f);
        acc[3] = fmaxf(acc[3] * sc.w + sh.w, 0.f);
    }
    acc[0] *= s; acc[1] *= s; acc[2] *= s; acc[3] *= s;
    for (int e = beg; e < end; e++) {
        int src = csr_src[e];
        ushortx4 hi = *(const ushortx4*)&zin[(size_t)src * 512 + c0];
        ushortx4 lo = *(const ushortx4*)&zin[(size_t)src * 512 + 256 + c0];
        float v0 = uf(hi[0]) + uf(lo[0]);
        float v1 = uf(hi[1]) + uf(lo[1]);
        float v2 = uf(hi[2]) + uf(lo[2]);
        float v3 = uf(hi[3]) + uf(lo[3]);
        if (useBN) {
            v0 = fmaxf(v0 * sc.x + sh.x, 0.f);
            v1 = fmaxf(v1 * sc.y + sh.y, 0.f);
            v2 = fmaxf(v2 * sc.z + sh.z, 0.f);
            v3 = fmaxf(v3 * sc.w + sh.w, 0.f);
        }
        acc[0] += v0; acc[1] += v1; acc[2] += v2; acc[3] += v3;
    }
    ushortx4 ho, lo2;
#pragma unroll
    for (int e = 0; e < 4; e++) {
        unsigned short hb, lb;
        split_bf16(acc[e], hb, lb);
        ho[e] = hb;
        lo2[e] = lb;
    }
    *(ushortx4*)&zout[(size_t)node * 512 + c0] = ho;
    *(ushortx4*)&zout[(size_t)node * 512 + 256 + c0] = lo2;
}

// ---------------- weight packing: fragment-order bf16 hi/lo ------------------
__global__ __launch_bounds__(256) void packW_kernel(const float* __restrict__ W1s,
                                                    const float* __restrict__ W2s,
                                                    short8* __restrict__ Wpk8) {
    int id = blockIdx.x * 256 + threadIdx.x;  // < 81920
    int lane = id & 63;
    int fid = (id >> 6) & 127;
    int w = id >> 13;  // 0..9
    int kt = fid >> 4, nt = fid & 15;
    const float* Wsrc = (w < 5) ? W1s + (size_t)w * HID * HID
                                : W2s + (size_t)(w - 5) * HID * HID;
    int k0 = kt * 32 + ((lane >> 4) << 3);
    int n = nt * 16 + (lane & 15);
    short8 hi, lo;
#pragma unroll
    for (int e = 0; e < 8; e++) {
        float v = Wsrc[(size_t)(k0 + e) * HID + n];
        unsigned short hb, lb;
        split_bf16(v, hb, lb);
        hi[e] = (short)hb;
        lo[e] = (short)lb;
    }
    size_t base = (size_t)w * 16384;
    Wpk8[base + (size_t)((0 * 8 + kt) * 16 + nt) * 64 + lane] = hi;
    Wpk8[base + (size_t)((1 * 8 + kt) * 16 + nt) * 64 + lane] = lo;
}

// ---------------- split-bf16 MFMA GEMM, async LDS staging --------------------
// A: split-plane u16 activations [M+pad][512]; C: same format.
__global__ __launch_bounds__(256, 2) void gemm_mfma_kernel(
    const u16* __restrict__ A, const short8* __restrict__ Wm,
    const float* __restrict__ bias, u16* __restrict__ C,
    int M, int doRelu, int doStats,
    float* __restrict__ sums, float* __restrict__ sumsq) {
    __shared__ char ldsbuf[65536];
    short8* As8 = (short8*)ldsbuf;            // 2048 frags (32KB)
    short8* Bs8 = (short8*)(ldsbuf + 32768);  // 2048 frags (32KB)
    float* cf = (float*)ldsbuf;               // epilogue: 128x128 fp32 tile
    int t = threadIdx.x;
    int lane = t & 63;
    int w = t >> 6;
    int wm = w >> 1, wn = w & 1;
    int m0 = blockIdx.x * 128;
    int n0 = blockIdx.y * 128;
    int y = blockIdx.y;

    floatx4 acc[4][4];
#pragma unroll
    for (int i = 0; i < 4; i++)
#pragma unroll
        for (int j = 0; j < 4; j++) acc[i][j] = (floatx4)0.0f;

    for (int ki = 0; ki < 4; ki++) {
        // ---- async stage: 32 A-frags + 32 B-frags, 16 issues per wave ----
#pragma unroll
        for (int q = 0; q < 8; q++) {
            int f = q * 4 + w;  // wave-uniform fragment id 0..31
            // A fragment: f = p*16 + tile, tile = ktl*8 + mt
            int p = f >> 4, tile = f & 15;
            int mt = tile & 7, ktl = tile >> 3;
            int m = m0 + mt * 16 + (lane & 15);
            int c = ki * 64 + ktl * 32 + ((lane >> 4) << 3);
            load16_to_lds(&A[(size_t)m * 512 + p * 256 + c], &As8[f * 64]);
            // B fragment: f = bp*16 + bktl*8 + ntl
            int ntl = f & 7, bktl = (f >> 3) & 1, bp = f >> 4;
            load16_to_lds(
                &Wm[((size_t)(bp * 8 + (ki * 2 + bktl)) * 16 + (y * 8 + ntl)) * 64 +
                    lane],
                &Bs8[((bp * 2 + bktl) * 8 + ntl) * 64]);
        }
        __syncthreads();
        // ---- compute ----
#pragma unroll
        for (int ktl = 0; ktl < 2; ktl++) {
            short8 ah[4], al[4], bh[4], bl[4];
#pragma unroll
            for (int i = 0; i < 4; i++) {
                ah[i] = As8[(0 * 16 + ktl * 8 + wm * 4 + i) * 64 + lane];
                al[i] = As8[(1 * 16 + ktl * 8 + wm * 4 + i) * 64 + lane];
            }
#pragma unroll
            for (int j = 0; j < 4; j++) {
                bh[j] = Bs8[((0 * 2 + ktl) * 8 + wn * 4 + j) * 64 + lane];
                bl[j] = Bs8[((1 * 2 + ktl) * 8 + wn * 4 + j) * 64 + lane];
            }
#pragma unroll
            for (int i = 0; i < 4; i++)
#pragma unroll
                for (int j = 0; j < 4; j++) {
                    acc[i][j] = __builtin_amdgcn_mfma_f32_16x16x32_bf16(
                        ah[i], bh[j], acc[i][j], 0, 0, 0);
                    acc[i][j] = __builtin_amdgcn_mfma_f32_16x16x32_bf16(
                        ah[i], bl[j], acc[i][j], 0, 0, 0);
                    acc[i][j] = __builtin_amdgcn_mfma_f32_16x16x32_bf16(
                        al[i], bh[j], acc[i][j], 0, 0, 0);
                }
        }
        __syncthreads();
    }

    // ---- epilogue: bias(+relu)(+stats) -> LDS fp32 tile ----
    int col = lane & 15;
    int rbase = (lane >> 4) * 4;
#pragma unroll
    for (int j = 0; j < 4; j++) {
        int lc = (wn * 4 + j) * 16 + col;  // local col 0..127
        int n = n0 + lc;
        float bv = bias[n];
        float csum = 0.f, csq = 0.f;
#pragma unroll
        for (int i = 0; i < 4; i++) {
            int lr = (wm * 4 + i) * 16 + rbase;  // local row
            int mb = m0 + lr;
#pragma unroll
            for (int r = 0; r < 4; r++) {
                float v = acc[i][j][r] + bv;
                if (doRelu) v = fmaxf(v, 0.0f);
                cf[(lr + r) * 128 + lc] = v;
                if (mb + r < M) {
                    csum += v;
                    csq += v * v;
                }
            }
        }
        if (doStats) {
            csum += __shfl_xor(csum, 16);
            csum += __shfl_xor(csum, 32);
            csq += __shfl_xor(csq, 16);
            csq += __shfl_xor(csq, 32);
            if ((lane >> 4) == 0) {
                atomicAdd(&sums[n], csum);
                atomicAdd(&sumsq[n], csq);
            }
        }
    }
    __syncthreads();
    // ---- coalesced split-bf16 write (conflict-free float4 LDS reads) ----
#pragma unroll
    for (int k = 0; k < 16; k++) {
        int fi = (k * 256 + t) * 4;  // flat float idx in 128x128 tile
        int row = fi >> 7, colc = fi & 127;
        int m = m0 + row;
        if (m >= M) continue;
        float4 v4 = *(float4*)&cf[fi];
        ushortx4 h4, l4;
        unsigned short hb, lb;
        split_bf16(v4.x, hb, lb); h4[0] = hb; l4[0] = lb;
        split_bf16(v4.y, hb, lb); h4[1] = hb; l4[1] = lb;
        split_bf16(v4.z, hb, lb); h4[2] = hb; l4[2] = lb;
        split_bf16(v4.w, hb, lb); h4[3] = hb; l4[3] = lb;
        *(ushortx4*)&C[(size_t)m * 512 + n0 + colc] = h4;
        *(ushortx4*)&C[(size_t)m * 512 + 256 + n0 + colc] = l4;
    }
}

__global__ void bnparams_kernel(const float* __restrict__ sums,
                                const float* __restrict__ sumsq,
                                const float* __restrict__ gammas,
                                const float* __restrict__ betas, int layer,
                                float* __restrict__ scale,
                                float* __restrict__ shift) {
    int c = threadIdx.x;
    float mu = sums[c] / (float)N_NODES;
    float var = sumsq[c] / (float)N_NODES - mu * mu;
    float rs = rsqrtf(var + BN_EPS);
    float g = gammas[layer * HID + c];
    scale[c] = rs * g;
    shift[c] = betas[layer * HID + c] - mu * rs * g;
}

// ---------------- pooling (batch sorted), fused final BN+relu ----------------
__global__ __launch_bounds__(256) void bounds_kernel(const int* __restrict__ batch,
                                                     int* __restrict__ start) {
    int g = blockIdx.x * 256 + threadIdx.x;
    if (g > N_GRAPHS) return;
    int lo = 0, hi = N_NODES;
    while (lo < hi) {
        int mid = (lo + hi) >> 1;
        if (batch[mid] < g) lo = mid + 1;
        else hi = mid;
    }
    start[g] = lo;
}

__global__ __launch_bounds__(256) void segpool_kernel(
    const u16* __restrict__ z, const int* __restrict__ start,
    const float* __restrict__ scale, const float* __restrict__ shift,
    float* __restrict__ pooled) {
    int g = blockIdx.x;
    int c = threadIdx.x;
    float sc = scale[c], sh = shift[c];
    int beg = start[g], end = start[g + 1];
    float s = 0.f;
    for (int n = beg; n < end; n++) {
        float v = uf(z[(size_t)n * 512 + c]) + uf(z[(size_t)n * 512 + 256 + c]);
        s += fmaxf(v * sc + sh, 0.f);
    }
    float inv = 1.0f / fmaxf((float)(end - beg), 1.0f);
    pooled[(size_t)g * HID + c] = s * inv;
}

// ---------------- readout ----------------------------------------------------
__global__ __launch_bounds__(256) void readout_kernel(
    const float* __restrict__ pooled, const float* __restrict__ Wr1,
    const float* __restrict__ br1, const float* __restrict__ Wr2,
    const float* __restrict__ br2, float* __restrict__ out) {
    __shared__ float p[HID];
    __shared__ float red[4];
    int g = blockIdx.x;
    int c = threadIdx.x;
    p[c] = pooled[(size_t)g * HID + c];
    __syncthreads();
    float acc = br1[c];
    for (int k = 0; k < HID; k++) acc += p[k] * Wr1[k * HID + c];
    acc = fmaxf(acc, 0.f);
    float v = acc * Wr2[c];
#pragma unroll
    for (int off = 32; off > 0; off >>= 1) v += __shfl_down(v, off, 64);
    if ((c & 63) == 0) red[c >> 6] = v;
    __syncthreads();
    if (c == 0) out[g] = red[0] + red[1] + red[2] + red[3] + br2[0];
}

extern "C" void kernel_launch(void* const* d_in, const int* in_sizes, int n_in,
                              void* d_out, int out_size, void* d_ws, size_t ws_size,
                              hipStream_t stream) {
    const float* x      = (const float*)d_in[0];
    const int*   ei     = (const int*)d_in[1];
    const int*   batch  = (const int*)d_in[2];
    const float* Wp     = (const float*)d_in[3];
    const float* bp     = (const float*)d_in[4];
    const float* eps    = (const float*)d_in[5];
    const float* W1s    = (const float*)d_in[6];
    const float* b1s    = (const float*)d_in[7];
    const float* W2s    = (const float*)d_in[8];
    const float* b2s    = (const float*)d_in[9];
    const float* gammas = (const float*)d_in[10];
    const float* betas  = (const float*)d_in[11];
    const float* Wr1    = (const float*)d_in[12];
    const float* br1    = (const float*)d_in[13];
    const float* Wr2    = (const float*)d_in[14];
    const float* br2    = (const float*)d_in[15];
    float* out = (float*)d_out;

    const size_t ROWS = (size_t)N_NODES + ROW_PAD;
    u16* bufA     = (u16*)d_ws;                  // ROWS*512 u16
    u16* bufB     = bufA + ROWS * 512;
    short8* Wpk8  = (short8*)(bufB + ROWS * 512);  // 10*16384 short8 = 2.62 MB
    float* sums   = (float*)(Wpk8 + 10 * 16384);
    float* sumsq  = sums + HID;
    float* scale  = sumsq + HID;
    float* shift  = scale + HID;
    float* pooled = shift + HID;
    int* start     = (int*)(pooled + (size_t)N_GRAPHS * HID);  // N_GRAPHS+1
    int* deg       = start + N_GRAPHS + 1;
    int* offs      = deg + N_NODES;        // N_NODES+1
    int* cursor    = offs + N_NODES + 1;
    int* csr_src   = cursor + N_NODES;
    int* blocksums = csr_src + N_EDGES;    // N_CHUNKS

    const dim3 GEMM_GRID((N_NODES + 127) / 128, 2);

    // ---- CSR build + weight packing (once per launch) ----
    hipMemsetAsync(deg, 0, N_NODES * sizeof(int), stream);
    hist_kernel<<<(N_EDGES + 255) / 256, 256, 0, stream>>>(ei, deg);
    scan1_kernel<<<N_CHUNKS, 256, 0, stream>>>(deg, offs, blocksums);
    scan2_kernel<<<1, 256, 0, stream>>>(blocksums);
    scan3_kernel<<<(N_NODES + 255) / 256, 256, 0, stream>>>(offs, blocksums,
                                                            cursor);
    fill_kernel<<<(N_EDGES + 255) / 256, 256, 0, stream>>>(ei, cursor, csr_src);
    packW_kernel<<<320, 256, 0, stream>>>(W1s, W2s, Wpk8);
    bounds_kernel<<<(N_GRAPHS + 1 + 255) / 256, 256, 0, stream>>>(batch, start);

    // h0 = x @ Wp + bp  -> bufA (split bf16)
    proj_kernel<<<(N_NODES + PROJ_CH - 1) / PROJ_CH, 256, 0, stream>>>(x, Wp, bp,
                                                                       bufA);

    u16* A = bufA;  // prev-layer z (or h0), pre-BN, split format
    u16* B = bufB;
    for (int l = 0; l < LAYERS; l++) {
        hipMemsetAsync(sums, 0, 2 * HID * sizeof(float), stream);
        // B = (1+eps)*f(A) + sum f(A[src]);  f = BN(l-1)+relu for l>0
        gather_kernel<<<(N_NODES + 3) / 4, 256, 0, stream>>>(
            offs, csr_src, A, B, eps, l, scale, shift, l > 0 ? 1 : 0);
        // A = relu(B @ W1 + b1)
        gemm_mfma_kernel<<<GEMM_GRID, 256, 0, stream>>>(
            B, Wpk8 + (size_t)l * 16384, b1s + l * HID, A, N_NODES, 1, 0,
            sums, sumsq);
        // B = A @ W2 + b2  (+ fused column stats)
        gemm_mfma_kernel<<<GEMM_GRID, 256, 0, stream>>>(
            A, Wpk8 + (size_t)(5 + l) * 16384, b2s + l * HID, B, N_NODES, 0, 1,
            sums, sumsq);
        bnparams_kernel<<<1, HID, 0, stream>>>(sums, sumsq, gammas, betas, l,
                                               scale, shift);
        u16* tmp = A; A = B; B = tmp;  // next layer's input = this z
    }

    // A holds z4 (pre-BN, split); segpool applies BN(4)+relu inline
    segpool_kernel<<<N_GRAPHS, 256, 0, stream>>>(A, start, scale, shift, pooled);
    readout_kernel<<<N_GRAPHS, 256, 0, stream>>>(pooled, Wr1, br1, Wr2, br2, out);
}